// Round 1
// baseline (3929.620 us; speedup 1.0000x reference)
//
#include <hip/hip_runtime.h>
#include <hip/hip_bf16.h>

#define T_SEQ 2048
#define D_MODEL 2048
#define NH 32
#define NKV 8
#define HDIM 64
#define BTROWS 4096   // B*T

// ---------- helpers ----------
__device__ __forceinline__ float us2f(unsigned short u) {
    unsigned int x = ((unsigned int)u) << 16;
    float f;
    __builtin_memcpy(&f, &x, 4);
    return f;
}

__device__ __forceinline__ void load4f(const float* p, float d[4]) {
    const float4 v = *reinterpret_cast<const float4*>(p);
    d[0] = v.x; d[1] = v.y; d[2] = v.z; d[3] = v.w;
}
__device__ __forceinline__ void load4f(const __hip_bfloat16* p, float d[4]) {
    const ushort4 v = *reinterpret_cast<const ushort4*>(p);
    d[0] = us2f(v.x); d[1] = us2f(v.y); d[2] = us2f(v.z); d[3] = us2f(v.w);
}

__device__ __forceinline__ void storeC(__hip_bfloat16* p, float v) { *p = __float2bfloat16(v); }
__device__ __forceinline__ void storeC(float* p, float v) { *p = v; }

// ---------- generic tiled GEMM: C[M,N] = A[M,K] @ W[K,N] ----------
// BM=BN=64, BK=16, 256 threads, 4x4 micro-tile per thread.
template <typename AT, typename CT>
__global__ __launch_bounds__(256) void gemm_tiled(const AT* __restrict__ A,
                                                  const float* __restrict__ W,
                                                  CT* __restrict__ C,
                                                  int M, int N, int K) {
    __shared__ float As[64][17];
    __shared__ float Ws[16][68];
    const int tid = threadIdx.x;
    const int row0 = blockIdx.y * 64;
    const int col0 = blockIdx.x * 64;
    const int ar = tid >> 2, ac = (tid & 3) * 4;   // A tile: 64x16
    const int wr = tid >> 4, wc = (tid & 15) * 4;  // W tile: 16x64
    const int ty = tid >> 4, tx = tid & 15;

    float acc[4][4] = {};

    for (int k0 = 0; k0 < K; k0 += 16) {
        float tmp[4];
        load4f(A + (size_t)(row0 + ar) * K + (k0 + ac), tmp);
        As[ar][ac + 0] = tmp[0];
        As[ar][ac + 1] = tmp[1];
        As[ar][ac + 2] = tmp[2];
        As[ar][ac + 3] = tmp[3];
        load4f(W + (size_t)(k0 + wr) * N + (col0 + wc), tmp);
        *reinterpret_cast<float4*>(&Ws[wr][wc]) = make_float4(tmp[0], tmp[1], tmp[2], tmp[3]);
        __syncthreads();
#pragma unroll
        for (int kk = 0; kk < 16; ++kk) {
            float a[4];
            a[0] = As[ty * 4 + 0][kk];
            a[1] = As[ty * 4 + 1][kk];
            a[2] = As[ty * 4 + 2][kk];
            a[3] = As[ty * 4 + 3][kk];
            const float4 b = *reinterpret_cast<const float4*>(&Ws[kk][tx * 4]);
#pragma unroll
            for (int i = 0; i < 4; ++i) {
                acc[i][0] += a[i] * b.x;
                acc[i][1] += a[i] * b.y;
                acc[i][2] += a[i] * b.z;
                acc[i][3] += a[i] * b.w;
            }
        }
        __syncthreads();
    }

#pragma unroll
    for (int i = 0; i < 4; ++i)
#pragma unroll
        for (int j = 0; j < 4; ++j)
            storeC(&C[(size_t)(row0 + ty * 4 + i) * N + (col0 + tx * 4 + j)], acc[i][j]);
}

// ---------- RoPE (in-place on bf16 buffer laid out [BTROWS, Hn*64]) ----------
__global__ __launch_bounds__(256) void rope_kernel(__hip_bfloat16* __restrict__ t,
                                                   const float* __restrict__ cosp,
                                                   const float* __restrict__ sinp,
                                                   int Hn) {
    const int total = BTROWS * Hn * 32;
    int idx = blockIdx.x * blockDim.x + threadIdx.x;
    if (idx >= total) return;
    const int p = idx & 31;
    const int hh = (idx >> 5) % Hn;
    const int row = idx / (32 * Hn);
    const int tpos = row & (T_SEQ - 1);
    const float c = cosp[tpos * 32 + p];
    const float s = sinp[tpos * 32 + p];
    const size_t base = (size_t)row * (Hn * 64) + hh * 64 + 2 * p;
    const float e = __bfloat162float(t[base]);
    const float o = __bfloat162float(t[base + 1]);
    t[base]     = __float2bfloat16(e * c - o * s);
    t[base + 1] = __float2bfloat16(e * s + o * c);
}

// ---------- flash attention (causal, GQA 4:1) ----------
// grid: (T/64, H, B); block: 256 threads. Each block: 64 q-rows of one head.
// thread t: q-row r = t>>2, 16-wide column/dim block jb = t&3.
__global__ __launch_bounds__(256) void attn_fwd(const __hip_bfloat16* __restrict__ q,
                                                const __hip_bfloat16* __restrict__ k,
                                                const __hip_bfloat16* __restrict__ v,
                                                __hip_bfloat16* __restrict__ o) {
    __shared__ float Qs[64][68];
    __shared__ float Ks[64][68];
    __shared__ float Vs[64][68];
    __shared__ float Ps[64][68];
    const int qt = blockIdx.x, h = blockIdx.y, b = blockIdx.z;
    const int g = h >> 2;  // kv group (N_REP=4)
    const int tid = threadIdx.x;
    const int r = tid >> 2, jb = tid & 3;
    const int qrow0 = qt * 64;

    for (int i = tid; i < 64 * 64; i += 256) {
        const int rr = i >> 6, dd = i & 63;
        Qs[rr][dd] = __bfloat162float(q[((size_t)(b * T_SEQ + qrow0 + rr)) * D_MODEL + h * HDIM + dd]);
    }

    float4 acc[4] = {};
    float m = -1e30f, l = 0.f;

    for (int kt = 0; kt <= qt; ++kt) {
        const int krow0 = kt * 64;
        __syncthreads();
        for (int i = tid; i < 64 * 64; i += 256) {
            const int rr = i >> 6, dd = i & 63;
            const size_t base = ((size_t)(b * T_SEQ + krow0 + rr)) * (NKV * HDIM) + g * HDIM + dd;
            Ks[rr][dd] = __bfloat162float(k[base]);
            Vs[rr][dd] = __bfloat162float(v[base]);
        }
        __syncthreads();

        float s[16];
        float mloc = -1e30f;
#pragma unroll 4
        for (int jj = 0; jj < 16; ++jj) {
            const int j = jb * 16 + jj;
            float sacc = 0.f;
#pragma unroll
            for (int d = 0; d < 64; d += 4) {
                const float4 qv = *reinterpret_cast<const float4*>(&Qs[r][d]);
                const float4 kv = *reinterpret_cast<const float4*>(&Ks[j][d]);
                sacc += qv.x * kv.x + qv.y * kv.y + qv.z * kv.z + qv.w * kv.w;
            }
            sacc *= 0.125f;
            if (krow0 + j > qrow0 + r) sacc = -1e30f;
            s[jj] = sacc;
            mloc = fmaxf(mloc, sacc);
        }
        mloc = fmaxf(mloc, __shfl_xor(mloc, 1));
        mloc = fmaxf(mloc, __shfl_xor(mloc, 2));
        const float mnew = fmaxf(m, mloc);
        const float scale = __expf(m - mnew);
        float psum = 0.f;
#pragma unroll
        for (int jj = 0; jj < 16; ++jj) {
            const float p = __expf(s[jj] - mnew);
            psum += p;
            Ps[r][jb * 16 + jj] = p;
        }
        psum += __shfl_xor(psum, 1);
        psum += __shfl_xor(psum, 2);
        l = l * scale + psum;
        m = mnew;
#pragma unroll
        for (int q4 = 0; q4 < 4; ++q4) {
            acc[q4].x *= scale; acc[q4].y *= scale; acc[q4].z *= scale; acc[q4].w *= scale;
        }
        // PV: reads Ps written by the same 4-lane group (same wave) — in-order LDS.
        for (int j = 0; j < 64; ++j) {
            const float p = Ps[r][j];
#pragma unroll
            for (int q4 = 0; q4 < 4; ++q4) {
                const float4 vv = *reinterpret_cast<const float4*>(&Vs[j][jb * 16 + q4 * 4]);
                acc[q4].x += p * vv.x; acc[q4].y += p * vv.y;
                acc[q4].z += p * vv.z; acc[q4].w += p * vv.w;
            }
        }
    }

    const float inv = 1.f / l;
    const size_t obase = ((size_t)(b * T_SEQ + qrow0 + r)) * D_MODEL + h * HDIM + jb * 16;
#pragma unroll
    for (int q4 = 0; q4 < 4; ++q4) {
        o[obase + q4 * 4 + 0] = __float2bfloat16(acc[q4].x * inv);
        o[obase + q4 * 4 + 1] = __float2bfloat16(acc[q4].y * inv);
        o[obase + q4 * 4 + 2] = __float2bfloat16(acc[q4].z * inv);
        o[obase + q4 * 4 + 3] = __float2bfloat16(acc[q4].w * inv);
    }
}

// ---------- launch ----------
extern "C" void kernel_launch(void* const* d_in, const int* in_sizes, int n_in,
                              void* d_out, int out_size, void* d_ws, size_t ws_size,
                              hipStream_t stream) {
    const float* x    = (const float*)d_in[0];
    const float* fcos = (const float*)d_in[1];
    const float* fsin = (const float*)d_in[2];
    // d_in[3] = mask (implemented as causal skip)
    const float* wq = (const float*)d_in[4];
    const float* wk = (const float*)d_in[5];
    const float* wv = (const float*)d_in[6];
    const float* wo = (const float*)d_in[7];
    float* out = (float*)d_out;

    char* ws = (char*)d_ws;
    __hip_bfloat16* qb  = (__hip_bfloat16*)(ws);                          // 4096x2048
    __hip_bfloat16* kb  = (__hip_bfloat16*)(ws + (size_t)16777216);       // 4096x512
    __hip_bfloat16* vb  = (__hip_bfloat16*)(ws + (size_t)20971520);       // 4096x512
    __hip_bfloat16* aob = (__hip_bfloat16*)(ws + (size_t)25165824);       // 4096x2048

    // QKV projections
    gemm_tiled<float, __hip_bfloat16><<<dim3(32, 64), 256, 0, stream>>>(x, wq, qb, BTROWS, 2048, 2048);
    gemm_tiled<float, __hip_bfloat16><<<dim3(8, 64), 256, 0, stream>>>(x, wk, kb, BTROWS, 512, 2048);
    gemm_tiled<float, __hip_bfloat16><<<dim3(8, 64), 256, 0, stream>>>(x, wv, vb, BTROWS, 512, 2048);

    // RoPE on q and k
    {
        const int totq = BTROWS * NH * 32;
        rope_kernel<<<(totq + 255) / 256, 256, 0, stream>>>(qb, fcos, fsin, NH);
        const int totk = BTROWS * NKV * 32;
        rope_kernel<<<(totk + 255) / 256, 256, 0, stream>>>(kb, fcos, fsin, NKV);
    }

    // attention
    attn_fwd<<<dim3(T_SEQ / 64, NH, 2), 256, 0, stream>>>(qb, kb, vb, aob);

    // output projection
    gemm_tiled<__hip_bfloat16, float><<<dim3(32, 64), 256, 0, stream>>>(aob, wo, out, BTROWS, 2048, 2048);
}

// Round 3
// 508.903 us; speedup vs baseline: 7.7217x; 7.7217x over previous
//
#include <hip/hip_runtime.h>
#include <hip/hip_bf16.h>

#define T_SEQ 2048
#define NROWS 4096     // B*T
#define NQKV  3072     // q(2048) + k(512) + v(512) columns

typedef __attribute__((ext_vector_type(8))) short short8;
typedef __attribute__((ext_vector_type(4))) float f32x4;

__device__ __forceinline__ unsigned short f2bf(float f) {
    unsigned u = __builtin_bit_cast(unsigned, f);
    u += 0x7FFF + ((u >> 16) & 1);
    return (unsigned short)(u >> 16);
}
__device__ __forceinline__ float bf2f(unsigned short s) {
    unsigned u = ((unsigned)s) << 16;
    return __builtin_bit_cast(float, u);
}

__device__ __forceinline__ void gload_lds16(const void* g, void* l) {
    __builtin_amdgcn_global_load_lds(
        (const __attribute__((address_space(1))) unsigned int*)g,
        (__attribute__((address_space(3))) unsigned int*)l,
        16, 0, 0);
}

__device__ __forceinline__ f32x4 mfma16(short8 a, short8 b, f32x4 c) {
    return __builtin_amdgcn_mfma_f32_16x16x32_bf16(a, b, c, 0, 0, 0);
}

// ---------------- transpose fp32[K][N] -> bf16[N][K] ----------------
__global__ __launch_bounds__(256) void transpose_f32_bf16(const float* __restrict__ S,
                                                          short* __restrict__ D,
                                                          int K, int N) {
    __shared__ float tile[32][33];
    const int n0 = blockIdx.x * 32, k0 = blockIdx.y * 32;
    const int t = threadIdx.x;
#pragma unroll
    for (int j = 0; j < 4; ++j) {
        int lin = t + 256 * j;
        int kk = lin >> 5, nn = lin & 31;
        tile[kk][nn] = S[(size_t)(k0 + kk) * N + n0 + nn];
    }
    __syncthreads();
#pragma unroll
    for (int j = 0; j < 4; ++j) {
        int lin = t + 256 * j;
        int nn = lin >> 5, kk = lin & 31;
        D[(size_t)(n0 + nn) * K + k0 + kk] = (short)f2bf(tile[kk][nn]);
    }
}

// ---------------- RoPE, in-place on bf16, row stride rs, col offset c0 ----------------
__global__ __launch_bounds__(256) void rope_kernel(unsigned short* __restrict__ t,
                                                   const float* __restrict__ cosp,
                                                   const float* __restrict__ sinp,
                                                   int Hn, int rs, int c0) {
    int idx = blockIdx.x * 256 + threadIdx.x;
    const int p = idx & 31;
    const int hh = (idx >> 5) % Hn;
    const int row = idx / (32 * Hn);
    const int tpos = row & (T_SEQ - 1);
    const float c = cosp[tpos * 32 + p];
    const float s = sinp[tpos * 32 + p];
    const size_t base = (size_t)row * rs + c0 + hh * 64 + 2 * p;
    float e = bf2f(t[base]), o = bf2f(t[base + 1]);
    t[base]     = f2bf(e * c - o * s);
    t[base + 1] = f2bf(e * s + o * c);
}

// ---------------- MFMA GEMM: C[M,N] = A[M,K] @ Bt[N,K]^T ----------------
// m97 structure: 128x128 tile, BK=32, 4 waves (2x2), linear LDS.
// A reg-staged (optionally fp32->bf16 convert); B via global_load_lds.
template <int A_F32, int STORE_F32>
__global__ __launch_bounds__(256) void gemm_mfma(const void* __restrict__ Av,
                                                 const short* __restrict__ Bt,
                                                 void* __restrict__ C,
                                                 int M, int N, int K) {
    __shared__ short As[128 * 32];
    __shared__ short Bs[128 * 32];
    const int tid = threadIdx.x;
    const int l = tid & 63, w = tid >> 6;
    const int wr = w >> 1, wc = w & 1;
    const int lm = l & 15, lg = l >> 4;
    const int row0 = blockIdx.y * 128, col0 = blockIdx.x * 128;

    f32x4 acc[4][4];
#pragma unroll
    for (int m = 0; m < 4; ++m)
#pragma unroll
        for (int n = 0; n < 4; ++n) acc[m][n] = (f32x4){0.f, 0.f, 0.f, 0.f};

    for (int k0 = 0; k0 < K; k0 += 32) {
        __syncthreads();
#pragma unroll
        for (int p = 0; p < 2; ++p) {
            const int c = tid + 256 * p;          // 0..511
            const int r = c >> 2, k8 = (c & 3) * 8;
            short8 av;
            if (A_F32) {
                const float* Af = (const float*)Av;
                const float4 f0 = *(const float4*)(Af + (size_t)(row0 + r) * K + k0 + k8);
                const float4 f1 = *(const float4*)(Af + (size_t)(row0 + r) * K + k0 + k8 + 4);
                av[0] = f2bf(f0.x); av[1] = f2bf(f0.y); av[2] = f2bf(f0.z); av[3] = f2bf(f0.w);
                av[4] = f2bf(f1.x); av[5] = f2bf(f1.y); av[6] = f2bf(f1.z); av[7] = f2bf(f1.w);
            } else {
                const short* Ab = (const short*)Av;
                av = *(const short8*)(Ab + (size_t)(row0 + r) * K + k0 + k8);
            }
            *(short8*)(&As[r * 32 + k8]) = av;
            gload_lds16(Bt + (size_t)(col0 + r) * K + k0 + k8, Bs + c * 8);
        }
        __syncthreads();
        short8 af[4], bfr[4];
#pragma unroll
        for (int m = 0; m < 4; ++m)
            af[m] = *(const short8*)(&As[(wr * 64 + m * 16 + lm) * 32 + lg * 8]);
#pragma unroll
        for (int n = 0; n < 4; ++n)
            bfr[n] = *(const short8*)(&Bs[(wc * 64 + n * 16 + lm) * 32 + lg * 8]);
#pragma unroll
        for (int m = 0; m < 4; ++m)
#pragma unroll
            for (int n = 0; n < 4; ++n)
                acc[m][n] = mfma16(af[m], bfr[n], acc[m][n]);
    }

#pragma unroll
    for (int m = 0; m < 4; ++m)
#pragma unroll
        for (int n = 0; n < 4; ++n)
#pragma unroll
            for (int r = 0; r < 4; ++r) {
                const int row = row0 + wr * 64 + m * 16 + lg * 4 + r;
                const int col = col0 + wc * 64 + n * 16 + lm;
                const float v = acc[m][n][r];
                if (STORE_F32) ((float*)C)[(size_t)row * N + col] = v;
                else ((unsigned short*)C)[(size_t)row * N + col] = f2bf(v);
            }
}

// ---------------- MFMA flash attention (causal, GQA 4:1) ----------------
// grid (T/64, H, B), 256 threads = 4 waves; wave w owns q-rows [64*qt+16w, +16).
// Verified-layout-only design: K row-major [64][72], V transposed Vt[d][j] [64][72],
// P per-wave [16][72] LDS round-trip. All MFMA frags are plain ds_read_b128.
__global__ __launch_bounds__(256) void attn_fwd(const short* __restrict__ qkv,
                                                unsigned short* __restrict__ aout) {
    __shared__ short Ks[64 * 72];
    __shared__ short Vt[64 * 72];
    __shared__ short Ps[4][16 * 72];
    const int qt = blockIdx.x, h = blockIdx.y, b = blockIdx.z;
    const int g = h >> 2;
    const int tid = threadIdx.x, l = tid & 63, w = tid >> 6;
    const int lm = l & 15, lg = l >> 4;
    const int qrow0 = qt * 64;

    short8 qf[2];
    {
        const size_t qbase = (size_t)(b * T_SEQ + qrow0 + w * 16 + lm) * NQKV + h * 64 + lg * 8;
        qf[0] = *(const short8*)(qkv + qbase);
        qf[1] = *(const short8*)(qkv + qbase + 32);
    }

    f32x4 acc[4];
#pragma unroll
    for (int dt = 0; dt < 4; ++dt) acc[dt] = (f32x4){0.f, 0.f, 0.f, 0.f};
    float mrow[4] = {-1e30f, -1e30f, -1e30f, -1e30f};
    float lrow[4] = {0.f, 0.f, 0.f, 0.f};

    for (int kt = 0; kt <= qt; ++kt) {
        const int krow0 = kt * 64;
        __syncthreads();
        // stage K row-major (coalesced short8 -> padded LDS rows)
#pragma unroll
        for (int p = 0; p < 2; ++p) {
            const int c = tid + 256 * p;          // 0..511
            const int r = c >> 3, c8 = (c & 7) * 8;
            const short8 kv = *(const short8*)(qkv + (size_t)(b * T_SEQ + krow0 + r) * NQKV + 2048 + g * 64 + c8);
            *(short8*)(&Ks[r * 72 + c8]) = kv;
        }
        // stage V transposed: Vt[d][j] = V[j][d]
#pragma unroll
        for (int p = 0; p < 2; ++p) {
            const int c = tid + 256 * p;
            const int j = c >> 3, d8 = (c & 7) * 8;
            const short8 vv = *(const short8*)(qkv + (size_t)(b * T_SEQ + krow0 + j) * NQKV + 2560 + g * 64 + d8);
#pragma unroll
            for (int e = 0; e < 8; ++e) Vt[(d8 + e) * 72 + j] = vv[e];
        }
        __syncthreads();

        // S = Q K^T : C row q=lg*4+r, col j=jt*16+lm
        f32x4 sv[4];
#pragma unroll
        for (int jt = 0; jt < 4; ++jt) {
            const int kr = jt * 16 + lm;
            const short8 k0f = *(const short8*)(&Ks[kr * 72 + lg * 8]);
            const short8 k1f = *(const short8*)(&Ks[kr * 72 + 32 + lg * 8]);
            f32x4 s = (f32x4){0.f, 0.f, 0.f, 0.f};
            s = mfma16(qf[0], k0f, s);
            s = mfma16(qf[1], k1f, s);
            sv[jt] = s;
        }

        // online softmax per local row r
        float pv[4][4];
#pragma unroll
        for (int r = 0; r < 4; ++r) {
            float mm = -1e30f;
#pragma unroll
            for (int jt = 0; jt < 4; ++jt) {
                float xx = sv[jt][r] * 0.125f;
                if (kt == qt && (krow0 + jt * 16 + lm) > (qrow0 + w * 16 + lg * 4 + r))
                    xx = -1e30f;
                pv[jt][r] = xx;
                mm = fmaxf(mm, xx);
            }
            mm = fmaxf(mm, __shfl_xor(mm, 1));
            mm = fmaxf(mm, __shfl_xor(mm, 2));
            mm = fmaxf(mm, __shfl_xor(mm, 4));
            mm = fmaxf(mm, __shfl_xor(mm, 8));
            const float mn = fmaxf(mrow[r], mm);
            const float sc = __expf(mrow[r] - mn);
            float ps = 0.f;
#pragma unroll
            for (int jt = 0; jt < 4; ++jt) {
                const float p = __expf(pv[jt][r] - mn);
                pv[jt][r] = p;
                ps += p;
            }
            ps += __shfl_xor(ps, 1);
            ps += __shfl_xor(ps, 2);
            ps += __shfl_xor(ps, 4);
            ps += __shfl_xor(ps, 8);
            lrow[r] = lrow[r] * sc + ps;
            mrow[r] = mn;
#pragma unroll
            for (int dt = 0; dt < 4; ++dt) acc[dt][r] *= sc;
        }

        // P -> per-wave LDS [q=16][j=64 (+8 pad)]
#pragma unroll
        for (int jt = 0; jt < 4; ++jt)
#pragma unroll
            for (int r = 0; r < 4; ++r)
                Ps[w][(lg * 4 + r) * 72 + jt * 16 + lm] = (short)f2bf(pv[jt][r]);

        // O += P @ V  (A: P[q=lm][j], B: V[j][d=lm] from Vt rows)
#pragma unroll
        for (int kb = 0; kb < 2; ++kb) {
            const short8 pa = *(const short8*)(&Ps[w][lm * 72 + kb * 32 + lg * 8]);
#pragma unroll
            for (int dt = 0; dt < 4; ++dt) {
                const short8 vf = *(const short8*)(&Vt[(dt * 16 + lm) * 72 + kb * 32 + lg * 8]);
                acc[dt] = mfma16(pa, vf, acc[dt]);
            }
        }
    }

    const size_t ob = (size_t)(b * T_SEQ + qrow0 + w * 16 + lg * 4) * 2048 + h * 64 + lm;
#pragma unroll
    for (int r = 0; r < 4; ++r) {
        const float inv = 1.0f / lrow[r];
#pragma unroll
        for (int dt = 0; dt < 4; ++dt)
            aout[ob + (size_t)r * 2048 + dt * 16] = f2bf(acc[dt][r] * inv);
    }
}

// ---------------- launch ----------------
extern "C" void kernel_launch(void* const* d_in, const int* in_sizes, int n_in,
                              void* d_out, int out_size, void* d_ws, size_t ws_size,
                              hipStream_t stream) {
    const float* x    = (const float*)d_in[0];
    const float* fcos = (const float*)d_in[1];
    const float* fsin = (const float*)d_in[2];
    const float* wq   = (const float*)d_in[4];
    const float* wk   = (const float*)d_in[5];
    const float* wv   = (const float*)d_in[6];
    const float* wo   = (const float*)d_in[7];

    short* ws0  = (short*)d_ws;
    short* qkvb = ws0;                    // [0, 24MB): 4096x3072 bf16
    short* wT   = ws0 + 12582912;         // [24MB, 36MB): wq^T|wk^T|wv^T  (3072x2048)
    short* aout = ws0 + 12582912;         // [24MB, 40MB): attn out, overwrites wT after GEMM1
    short* woT  = ws0;                    // [0, 8MB): wo^T, overwrites qkvb after attn
    // peak footprint = 40MB (same as round-1-proven layout)

    // 1. weight transposes (fp32 -> bf16, [K][N] -> [N][K])
    transpose_f32_bf16<<<dim3(64, 64), 256, 0, stream>>>(wq, wT, 2048, 2048);
    transpose_f32_bf16<<<dim3(16, 64), 256, 0, stream>>>(wk, wT + 2048 * 2048, 2048, 512);
    transpose_f32_bf16<<<dim3(16, 64), 256, 0, stream>>>(wv, wT + 2560 * 2048, 2048, 512);
    // 2. fused QKV projection: qkvb = x @ wT^T (A fp32 reg-staged)
    gemm_mfma<1, 0><<<dim3(24, 32), 256, 0, stream>>>(x, wT, qkvb, NROWS, NQKV, 2048);
    // 3. RoPE on q and k inside qkvb
    rope_kernel<<<16384, 256, 0, stream>>>((unsigned short*)qkvb, fcos, fsin, 32, NQKV, 0);
    rope_kernel<<<4096, 256, 0, stream>>>((unsigned short*)qkvb, fcos, fsin, 8, NQKV, 2048);
    // 4. attention
    attn_fwd<<<dim3(32, 32, 2), 256, 0, stream>>>(qkvb, (unsigned short*)aout);
    // 5. wo^T (after attn: qkvb region is dead)
    transpose_f32_bf16<<<dim3(64, 64), 256, 0, stream>>>(wo, woT, 2048, 2048);
    // 6. output projection: d_out = aout @ woT^T (fp32 store)
    gemm_mfma<0, 1><<<dim3(16, 32), 256, 0, stream>>>(aout, woT, d_out, NROWS, 2048, 2048);
}

// Round 4
// 317.745 us; speedup vs baseline: 12.3672x; 1.6016x over previous
//
#include <hip/hip_runtime.h>
#include <hip/hip_bf16.h>

#define T_SEQ 2048
#define NROWS 4096     // B*T
#define QKS   2560     // qkv buffer row stride: q(2048) + k(512)

typedef __attribute__((ext_vector_type(8))) short short8;
typedef __attribute__((ext_vector_type(4))) float f32x4;
typedef __attribute__((ext_vector_type(16))) float f32x16;
typedef __attribute__((ext_vector_type(2))) int i32x2;
typedef __attribute__((ext_vector_type(2))) unsigned int u32x2;

__device__ __forceinline__ unsigned short f2bf(float f) {
    unsigned u = __builtin_bit_cast(unsigned, f);
    u += 0x7FFF + ((u >> 16) & 1);
    return (unsigned short)(u >> 16);
}
__device__ __forceinline__ float bf2f(unsigned short s) {
    unsigned u = ((unsigned)s) << 16;
    return __builtin_bit_cast(float, u);
}

__device__ __forceinline__ void gload_lds16(const void* g, void* l) {
    __builtin_amdgcn_global_load_lds(
        (const __attribute__((address_space(1))) unsigned int*)g,
        (__attribute__((address_space(3))) unsigned int*)l,
        16, 0, 0);
}

__device__ __forceinline__ f32x4 mfma16(short8 a, short8 b, f32x4 c) {
    return __builtin_amdgcn_mfma_f32_16x16x32_bf16(a, b, c, 0, 0, 0);
}
__device__ __forceinline__ f32x16 mfma32(short8 a, short8 b, f32x16 c) {
    return __builtin_amdgcn_mfma_f32_32x32x16_bf16(a, b, c, 0, 0, 0);
}

__device__ __forceinline__ unsigned cvtpk_bf16(float lo, float hi) {
    unsigned r;
    asm("v_cvt_pk_bf16_f32 %0, %1, %2" : "=v"(r) : "v"(lo), "v"(hi));
    return r;
}

__device__ __forceinline__ short8 frag_from_u32(unsigned w0, unsigned w1, unsigned w2, unsigned w3) {
    union { unsigned u[4]; short8 s; } t;
    t.u[0] = w0; t.u[1] = w1; t.u[2] = w2; t.u[3] = w3;
    return t.s;
}

// ---------------- transpose fp32[K][N] -> bf16[N][K] ----------------
__global__ __launch_bounds__(256) void transpose_f32_bf16(const float* __restrict__ S,
                                                          short* __restrict__ D,
                                                          int K, int N) {
    __shared__ float tile[32][33];
    const int n0 = blockIdx.x * 32, k0 = blockIdx.y * 32;
    const int t = threadIdx.x;
#pragma unroll
    for (int j = 0; j < 4; ++j) {
        int lin = t + 256 * j;
        int kk = lin >> 5, nn = lin & 31;
        tile[kk][nn] = S[(size_t)(k0 + kk) * N + n0 + nn];
    }
    __syncthreads();
#pragma unroll
    for (int j = 0; j < 4; ++j) {
        int lin = t + 256 * j;
        int nn = lin >> 5, kk = lin & 31;
        D[(size_t)(n0 + nn) * K + k0 + kk] = (short)f2bf(tile[kk][nn]);
    }
}

// ---------------- transpose bf16[R][C] -> bf16[C][R] ----------------
__global__ __launch_bounds__(256) void transpose_bf16(const short* __restrict__ S,
                                                      short* __restrict__ D,
                                                      int R, int Cc) {
    __shared__ short tile[32][33];
    const int c0 = blockIdx.x * 32, r0 = blockIdx.y * 32;
    const int t = threadIdx.x;
#pragma unroll
    for (int j = 0; j < 4; ++j) {
        int lin = t + 256 * j;
        int rr = lin >> 5, cc = lin & 31;
        tile[rr][cc] = S[(size_t)(r0 + rr) * Cc + c0 + cc];
    }
    __syncthreads();
#pragma unroll
    for (int j = 0; j < 4; ++j) {
        int lin = t + 256 * j;
        int cc = lin >> 5, rr = lin & 31;
        D[(size_t)(c0 + cc) * R + r0 + rr] = tile[rr][cc];
    }
}

// ---------------- RoPE, in-place on bf16, row stride rs, col offset c0 ----------------
__global__ __launch_bounds__(256) void rope_kernel(unsigned short* __restrict__ t,
                                                   const float* __restrict__ cosp,
                                                   const float* __restrict__ sinp,
                                                   int Hn, int rs, int c0) {
    int idx = blockIdx.x * 256 + threadIdx.x;
    const int p = idx & 31;
    const int hh = (idx >> 5) % Hn;
    const int row = idx / (32 * Hn);
    const int tpos = row & (T_SEQ - 1);
    const float c = cosp[tpos * 32 + p];
    const float s = sinp[tpos * 32 + p];
    const size_t base = (size_t)row * rs + c0 + hh * 64 + 2 * p;
    float e = bf2f(t[base]), o = bf2f(t[base + 1]);
    t[base]     = f2bf(e * c - o * s);
    t[base + 1] = f2bf(e * s + o * c);
}

// ---------------- MFMA GEMM: C[M,N] = A[M,K] @ Bt[N,K]^T ----------------
// m97 structure: 128x128 tile, BK=32, 4 waves (2x2), linear LDS.
// cols >= nsplit go (bf16) to Cv with row stride 512 at col-nsplit.
template <int A_F32, int STORE_F32>
__global__ __launch_bounds__(256) void gemm_mfma(const void* __restrict__ Av,
                                                 const short* __restrict__ Bt,
                                                 void* __restrict__ C, int ldc,
                                                 short* __restrict__ Cv, int nsplit,
                                                 int M, int N, int K) {
    __shared__ short As[128 * 32];
    __shared__ short Bs[128 * 32];
    const int tid = threadIdx.x;
    const int l = tid & 63, w = tid >> 6;
    const int wr = w >> 1, wc = w & 1;
    const int lm = l & 15, lg = l >> 4;
    const int row0 = blockIdx.y * 128, col0 = blockIdx.x * 128;

    f32x4 acc[4][4];
#pragma unroll
    for (int m = 0; m < 4; ++m)
#pragma unroll
        for (int n = 0; n < 4; ++n) acc[m][n] = (f32x4){0.f, 0.f, 0.f, 0.f};

    for (int k0 = 0; k0 < K; k0 += 32) {
        __syncthreads();
#pragma unroll
        for (int p = 0; p < 2; ++p) {
            const int c = tid + 256 * p;          // 0..511
            const int r = c >> 2, k8 = (c & 3) * 8;
            if (A_F32) {
                const float* Af = (const float*)Av;
                const float4 f0 = *(const float4*)(Af + (size_t)(row0 + r) * K + k0 + k8);
                const float4 f1 = *(const float4*)(Af + (size_t)(row0 + r) * K + k0 + k8 + 4);
                short8 av;
                av[0] = f2bf(f0.x); av[1] = f2bf(f0.y); av[2] = f2bf(f0.z); av[3] = f2bf(f0.w);
                av[4] = f2bf(f1.x); av[5] = f2bf(f1.y); av[6] = f2bf(f1.z); av[7] = f2bf(f1.w);
                *(short8*)(&As[r * 32 + k8]) = av;
            } else {
                const short* Ab = (const short*)Av;
                gload_lds16(Ab + (size_t)(row0 + r) * K + k0 + k8, As + c * 8);
            }
            gload_lds16(Bt + (size_t)(col0 + r) * K + k0 + k8, Bs + c * 8);
        }
        __syncthreads();
        short8 af[4], bfr[4];
#pragma unroll
        for (int m = 0; m < 4; ++m)
            af[m] = *(const short8*)(&As[(wr * 64 + m * 16 + lm) * 32 + lg * 8]);
#pragma unroll
        for (int n = 0; n < 4; ++n)
            bfr[n] = *(const short8*)(&Bs[(wc * 64 + n * 16 + lm) * 32 + lg * 8]);
#pragma unroll
        for (int m = 0; m < 4; ++m)
#pragma unroll
            for (int n = 0; n < 4; ++n)
                acc[m][n] = mfma16(af[m], bfr[n], acc[m][n]);
    }

    const bool vreg = (!STORE_F32) && (col0 >= nsplit);
#pragma unroll
    for (int m = 0; m < 4; ++m)
#pragma unroll
        for (int n = 0; n < 4; ++n) {
            if (vreg) {
                // V region: store transposed-friendly into Cv[row][col-nsplit], stride 512
#pragma unroll
                for (int r = 0; r < 4; ++r) {
                    const int row = row0 + wr * 64 + m * 16 + lg * 4 + r;
                    const int col = col0 + wc * 64 + n * 16 + lm - nsplit;
                    Cv[(size_t)row * 512 + col] = (short)f2bf(acc[m][n][r]);
                }
            } else {
#pragma unroll
                for (int r = 0; r < 4; ++r) {
                    const int row = row0 + wr * 64 + m * 16 + lg * 4 + r;
                    const int col = col0 + wc * 64 + n * 16 + lm;
                    const float v = acc[m][n][r];
                    if (STORE_F32) ((float*)C)[(size_t)row * ldc + col] = v;
                    else ((unsigned short*)C)[(size_t)row * ldc + col] = f2bf(v);
                }
            }
        }
}

// ---------------- MFMA flash attention (causal, GQA 4:1), 32x32x16 ----------------
// grid (16, 32, 2): qt = 15 - bx (descending), h, b. 256 threads = 4 waves.
// Wave w owns q rows [qt*128 + w*32, +32). Lane: n = l&31 (its q), hi = l>>5.
// S^T = K·Q^T (C col = q = n). P built in-register via cvt_pk + permlane32_swap.
// O^T = V^T·P^T (C col = q = n) -> rescale lane-local.
__global__ __launch_bounds__(256) void attn_fwd(const short* __restrict__ qkv,
                                                const short* __restrict__ vt,
                                                unsigned short* __restrict__ aout) {
    __shared__ short Ks[2][64 * 64];
    __shared__ short Vs[2][64 * 64];
    const int qt = 15 - blockIdx.x, h = blockIdx.y, b = blockIdx.z;
    const int g = h >> 2;
    const int tid = threadIdx.x, l = tid & 63, w = tid >> 6;
    const int n = l & 31, hi = l >> 5;
    const int qrow0w = qt * 128 + w * 32;
    const int qg = qrow0w + n;

    // Q fragments: qb[ks] = Q[qg][ks*16 + hi*8 .. +8]
    short8 qb[4];
    {
        const size_t qbase = (size_t)(b * T_SEQ + qg) * QKS + h * 64 + hi * 8;
        qb[0] = *(const short8*)(qkv + qbase);
        qb[1] = *(const short8*)(qkv + qbase + 16);
        qb[2] = *(const short8*)(qkv + qbase + 32);
        qb[3] = *(const short8*)(qkv + qbase + 48);
    }

    f32x16 acc0 = {}, acc1 = {};
    float m_run = -1e30f, l_run = 0.f;

    const int ntiles = 2 * qt + 2;
    const size_t krow_base = (size_t)(b * T_SEQ) * QKS + 2048 + g * 64;
    const size_t vrow_base = (size_t)(g * 64) * NROWS + b * T_SEQ;

    // ---- staging (gload_lds, source-granule XOR swizzle S(r,g)=g^(r&7)) ----
    auto STAGE = [&](int buf, int kt) {
        const int krow0 = kt * 64;
#pragma unroll
        for (int p = 0; p < 2; ++p) {
            const int c = p * 256 + tid;        // 0..511
            const int r = c >> 3, gk = c & 7;
            const int gs = gk ^ (r & 7);
            gload_lds16(qkv + krow_base + (size_t)(krow0 + r) * QKS + gs * 8,
                        &Ks[buf][c * 8]);
            gload_lds16(vt + vrow_base + (size_t)r * NROWS + krow0 + gs * 8,
                        &Vs[buf][c * 8]);
        }
    };

    STAGE(0, 0);
    asm volatile("s_waitcnt vmcnt(0)" ::: "memory");
    __syncthreads();

    for (int kt = 0; kt < ntiles; ++kt) {
        const int cur = kt & 1;
        if (kt + 1 < ntiles) STAGE(cur ^ 1, kt + 1);

        const int krow0 = kt * 64;
        const bool active = (krow0 <= qrow0w + 31);
        if (active) {
            const short* KsB = &Ks[cur][0];
            const short* VsB = &Vs[cur][0];

            // ---- S^T = K Q^T ----
            f32x16 s0 = {}, s1 = {};
#pragma unroll
            for (int ks = 0; ks < 4; ++ks) {
                const int perm = ((2 * ks + hi) ^ (n & 7)) * 8;
                const short8 kf0 = *(const short8*)(KsB + n * 64 + perm);
                const short8 kf1 = *(const short8*)(KsB + (32 + n) * 64 + perm);
                s0 = mfma32(kf0, qb[ks], s0);
                s1 = mfma32(kf1, qb[ks], s1);
            }

            // ---- causal mask ----
            if (krow0 + 63 > qrow0w) {
#pragma unroll
                for (int r = 0; r < 16; ++r) {
                    const int jj = krow0 + (r & 3) + 8 * (r >> 2) + 4 * hi;
                    if (jj > qg) s0[r] = -1e30f;
                    if (jj + 32 > qg) s1[r] = -1e30f;
                }
            }

            // ---- online softmax (lane-local + one shfl across l^32) ----
            float mx = s0[0];
#pragma unroll
            for (int r = 1; r < 16; ++r) mx = fmaxf(mx, s0[r]);
#pragma unroll
            for (int r = 0; r < 16; ++r) mx = fmaxf(mx, s1[r]);
            mx = fmaxf(mx, __shfl_xor(mx, 32));
            const float mn = fmaxf(m_run, mx * 0.125f);
            const float sc = __expf(m_run - mn);
            float ps = 0.f;
#pragma unroll
            for (int r = 0; r < 16; ++r) {
                const float p0 = __expf(__builtin_fmaf(s0[r], 0.125f, -mn));
                s0[r] = p0; ps += p0;
            }
#pragma unroll
            for (int r = 0; r < 16; ++r) {
                const float p1 = __expf(__builtin_fmaf(s1[r], 0.125f, -mn));
                s1[r] = p1; ps += p1;
            }
            ps += __shfl_xor(ps, 32);
            l_run = l_run * sc + ps;
            m_run = mn;
#pragma unroll
            for (int r = 0; r < 16; ++r) { acc0[r] *= sc; acc1[r] *= sc; }

            // ---- PV: O^T += V^T P^T, P-frags built in-register ----
#define PV_STEP(KS, SV)                                                          \
            {                                                                    \
                const unsigned pL0 = cvtpk_bf16(SV[((KS)&1)*8+0], SV[((KS)&1)*8+1]); \
                const unsigned pL1 = cvtpk_bf16(SV[((KS)&1)*8+2], SV[((KS)&1)*8+3]); \
                const unsigned pH0 = cvtpk_bf16(SV[((KS)&1)*8+4], SV[((KS)&1)*8+5]); \
                const unsigned pH1 = cvtpk_bf16(SV[((KS)&1)*8+6], SV[((KS)&1)*8+7]); \
                const i32x2 sL0 = __builtin_amdgcn_permlane32_swap((int)pL0, (int)pL0, false, false); \
                const i32x2 sL1 = __builtin_amdgcn_permlane32_swap((int)pL1, (int)pL1, false, false); \
                const i32x2 sH0 = __builtin_amdgcn_permlane32_swap((int)pH0, (int)pH0, false, false); \
                const i32x2 sH1 = __builtin_amdgcn_permlane32_swap((int)pH1, (int)pH1, false, false); \
                const unsigned w0 = hi ? (unsigned)sH0.x : (unsigned)sL0.x;      \
                const unsigned w1 = hi ? (unsigned)sH1.x : (unsigned)sL1.x;      \
                const unsigned w2 = hi ? (unsigned)sH0.y : (unsigned)sL0.y;      \
                const unsigned w3 = hi ? (unsigned)sH1.y : (unsigned)sL1.y;      \
                const short8 pfrag = frag_from_u32(w0, w1, w2, w3);              \
                const int permv = ((2 * (KS) + hi) ^ (n & 7)) * 8;               \
                const short8 vf0 = *(const short8*)(VsB + n * 64 + permv);       \
                const short8 vf1 = *(const short8*)(VsB + (32 + n) * 64 + permv);\
                acc0 = mfma32(vf0, pfrag, acc0);                                 \
                acc1 = mfma32(vf1, pfrag, acc1);                                 \
            }
            PV_STEP(0, s0)
            PV_STEP(1, s0)
            PV_STEP(2, s1)
            PV_STEP(3, s1)
#undef PV_STEP
        }

        asm volatile("s_waitcnt vmcnt(0)" ::: "memory");
        __syncthreads();
    }

    // ---- epilogue: O[q][d], d = dt*32 + rg*8 + hi*4 + (0..3) ----
    const float invl = 1.0f / l_run;
    const size_t orow = (size_t)(b * T_SEQ + qg) * 2048 + h * 64;
#pragma unroll
    for (int rg = 0; rg < 4; ++rg) {
        u32x2 pk0, pk1;
        pk0.x = (unsigned)f2bf(acc0[rg * 4 + 0] * invl) | ((unsigned)f2bf(acc0[rg * 4 + 1] * invl) << 16);
        pk0.y = (unsigned)f2bf(acc0[rg * 4 + 2] * invl) | ((unsigned)f2bf(acc0[rg * 4 + 3] * invl) << 16);
        pk1.x = (unsigned)f2bf(acc1[rg * 4 + 0] * invl) | ((unsigned)f2bf(acc1[rg * 4 + 1] * invl) << 16);
        pk1.y = (unsigned)f2bf(acc1[rg * 4 + 2] * invl) | ((unsigned)f2bf(acc1[rg * 4 + 3] * invl) << 16);
        *(u32x2*)(aout + orow + rg * 8 + hi * 4) = pk0;
        *(u32x2*)(aout + orow + 32 + rg * 8 + hi * 4) = pk1;
    }
}

// ---------------- launch ----------------
extern "C" void kernel_launch(void* const* d_in, const int* in_sizes, int n_in,
                              void* d_out, int out_size, void* d_ws, size_t ws_size,
                              hipStream_t stream) {
    const float* x    = (const float*)d_in[0];
    const float* fcos = (const float*)d_in[1];
    const float* fsin = (const float*)d_in[2];
    const float* wq   = (const float*)d_in[4];
    const float* wk   = (const float*)d_in[5];
    const float* wv   = (const float*)d_in[6];
    const float* wo   = (const float*)d_in[7];

    short* ws0  = (short*)d_ws;
    short* qkvb = ws0;                    // [0, 20MB): 4096 x 2560 (q|k)
    short* vt   = ws0 + 10485760;         // [20, 24MB): V^T 512 x 4096
    short* wT   = ws0 + 12582912;         // [24, 36MB): wq^T|wk^T|wv^T (3072 x 2048)
    short* vbuf = ws0 + 18874368;         // [36, 40MB): V 4096 x 512
    short* aout = ws0 + 12582912;         // [24, 40MB): attn out (after wT/vbuf dead)
    short* woT  = ws0;                    // [0, 8MB): wo^T (after qkvb dead)

    // 1. weight transposes (fp32 -> bf16, [K][N] -> [N][K])
    transpose_f32_bf16<<<dim3(64, 64), 256, 0, stream>>>(wq, wT, 2048, 2048);
    transpose_f32_bf16<<<dim3(16, 64), 256, 0, stream>>>(wk, wT + 2048 * 2048, 2048, 512);
    transpose_f32_bf16<<<dim3(16, 64), 256, 0, stream>>>(wv, wT + 2560 * 2048, 2048, 512);
    // 2. fused QKV projection: q,k -> qkvb (stride 2560); v -> vbuf (stride 512)
    gemm_mfma<1, 0><<<dim3(24, 32), 256, 0, stream>>>(x, wT, qkvb, QKS, vbuf, 2560,
                                                      NROWS, 3072, 2048);
    // 3. RoPE on q and k
    rope_kernel<<<16384, 256, 0, stream>>>((unsigned short*)qkvb, fcos, fsin, 32, QKS, 0);
    rope_kernel<<<4096, 256, 0, stream>>>((unsigned short*)qkvb, fcos, fsin, 8, QKS, 2048);
    // 4. V -> V^T
    transpose_bf16<<<dim3(16, 128), 256, 0, stream>>>(vbuf, vt, NROWS, 512);
    // 5. attention
    attn_fwd<<<dim3(16, 32, 2), 256, 0, stream>>>(qkvb, vt, (unsigned short*)aout);
    // 6. wo^T (qkvb region dead now)
    transpose_f32_bf16<<<dim3(64, 64), 256, 0, stream>>>(wo, woT, 2048, 2048);
    // 7. output projection
    gemm_mfma<0, 1><<<dim3(16, 32), 256, 0, stream>>>(aout, woT, d_out, 2048, nullptr, 1 << 30,
                                                      NROWS, 2048, 2048);
}

// Round 5
// 244.753 us; speedup vs baseline: 16.0554x; 1.2982x over previous
//
#include <hip/hip_runtime.h>
#include <hip/hip_bf16.h>

#define T_SEQ 2048
#define NROWS 4096     // B*T
#define QKS   2560     // qkv buffer row stride: q(2048) + k(512)

typedef __attribute__((ext_vector_type(8))) short short8;
typedef __attribute__((ext_vector_type(4))) float f32x4;
typedef __attribute__((ext_vector_type(16))) float f32x16;
typedef __attribute__((ext_vector_type(2))) int i32x2;
typedef __attribute__((ext_vector_type(2))) unsigned int u32x2;

#define KC 0.18033688f   // 0.125 * log2(e)

__device__ __forceinline__ unsigned short f2bf(float f) {
    unsigned u = __builtin_bit_cast(unsigned, f);
    u += 0x7FFF + ((u >> 16) & 1);
    return (unsigned short)(u >> 16);
}
__device__ __forceinline__ float bf2f(unsigned short s) {
    unsigned u = ((unsigned)s) << 16;
    return __builtin_bit_cast(float, u);
}

__device__ __forceinline__ void gload_lds16(const void* g, void* l) {
    __builtin_amdgcn_global_load_lds(
        (const __attribute__((address_space(1))) unsigned int*)g,
        (__attribute__((address_space(3))) unsigned int*)l,
        16, 0, 0);
}

__device__ __forceinline__ f32x4 mfma16(short8 a, short8 b, f32x4 c) {
    return __builtin_amdgcn_mfma_f32_16x16x32_bf16(a, b, c, 0, 0, 0);
}
__device__ __forceinline__ f32x16 mfma32(short8 a, short8 b, f32x16 c) {
    return __builtin_amdgcn_mfma_f32_32x32x16_bf16(a, b, c, 0, 0, 0);
}

__device__ __forceinline__ unsigned cvtpk_bf16(float lo, float hi) {
    unsigned r;
    asm("v_cvt_pk_bf16_f32 %0, %1, %2" : "=v"(r) : "v"(lo), "v"(hi));
    return r;
}

__device__ __forceinline__ short8 frag_from_u32(unsigned w0, unsigned w1, unsigned w2, unsigned w3) {
    union { unsigned u[4]; short8 s; } t;
    t.u[0] = w0; t.u[1] = w1; t.u[2] = w2; t.u[3] = w3;
    return t.s;
}

// ---------------- transpose fp32[K][N] -> bf16[N][K] ----------------
__global__ __launch_bounds__(256) void transpose_f32_bf16(const float* __restrict__ S,
                                                          short* __restrict__ D,
                                                          int K, int N) {
    __shared__ float tile[32][33];
    const int n0 = blockIdx.x * 32, k0 = blockIdx.y * 32;
    const int t = threadIdx.x;
#pragma unroll
    for (int j = 0; j < 4; ++j) {
        int lin = t + 256 * j;
        int kk = lin >> 5, nn = lin & 31;
        tile[kk][nn] = S[(size_t)(k0 + kk) * N + n0 + nn];
    }
    __syncthreads();
#pragma unroll
    for (int j = 0; j < 4; ++j) {
        int lin = t + 256 * j;
        int nn = lin >> 5, kk = lin & 31;
        D[(size_t)(n0 + nn) * K + k0 + kk] = (short)f2bf(tile[kk][nn]);
    }
}

// ---------------- transpose bf16[R][C] -> bf16[C][R] ----------------
__global__ __launch_bounds__(256) void transpose_bf16(const short* __restrict__ S,
                                                      short* __restrict__ D,
                                                      int R, int Cc) {
    __shared__ short tile[32][33];
    const int c0 = blockIdx.x * 32, r0 = blockIdx.y * 32;
    const int t = threadIdx.x;
#pragma unroll
    for (int j = 0; j < 4; ++j) {
        int lin = t + 256 * j;
        int rr = lin >> 5, cc = lin & 31;
        tile[rr][cc] = S[(size_t)(r0 + rr) * Cc + c0 + cc];
    }
    __syncthreads();
#pragma unroll
    for (int j = 0; j < 4; ++j) {
        int lin = t + 256 * j;
        int cc = lin >> 5, rr = lin & 31;
        D[(size_t)(c0 + cc) * R + r0 + rr] = tile[rr][cc];
    }
}

// ---------------- RoPE, in-place on bf16, row stride rs, col offset c0 ----------------
__global__ __launch_bounds__(256) void rope_kernel(unsigned short* __restrict__ t,
                                                   const float* __restrict__ cosp,
                                                   const float* __restrict__ sinp,
                                                   int Hn, int rs, int c0) {
    int idx = blockIdx.x * 256 + threadIdx.x;
    const int p = idx & 31;
    const int hh = (idx >> 5) % Hn;
    const int row = idx / (32 * Hn);
    const int tpos = row & (T_SEQ - 1);
    const float c = cosp[tpos * 32 + p];
    const float s = sinp[tpos * 32 + p];
    const size_t base = (size_t)row * rs + c0 + hh * 64 + 2 * p;
    float e = bf2f(t[base]), o = bf2f(t[base + 1]);
    t[base]     = f2bf(e * c - o * s);
    t[base + 1] = f2bf(e * s + o * c);
}

// ---------------- MFMA GEMM: C[M,N] = A[M,K] @ Bt[N,K]^T ----------------
// m97 structure: 128x128 tile, BK=32, 4 waves (2x2), linear LDS.
// cols >= nsplit go (bf16) to Cv with row stride 512 at col-nsplit.
template <int A_F32, int STORE_F32>
__global__ __launch_bounds__(256) void gemm_mfma(const void* __restrict__ Av,
                                                 const short* __restrict__ Bt,
                                                 void* __restrict__ C, int ldc,
                                                 short* __restrict__ Cv, int nsplit,
                                                 int M, int N, int K) {
    __shared__ short As[128 * 32];
    __shared__ short Bs[128 * 32];
    const int tid = threadIdx.x;
    const int l = tid & 63, w = tid >> 6;
    const int wr = w >> 1, wc = w & 1;
    const int lm = l & 15, lg = l >> 4;
    const int row0 = blockIdx.y * 128, col0 = blockIdx.x * 128;

    f32x4 acc[4][4];
#pragma unroll
    for (int m = 0; m < 4; ++m)
#pragma unroll
        for (int n = 0; n < 4; ++n) acc[m][n] = (f32x4){0.f, 0.f, 0.f, 0.f};

    for (int k0 = 0; k0 < K; k0 += 32) {
        __syncthreads();
#pragma unroll
        for (int p = 0; p < 2; ++p) {
            const int c = tid + 256 * p;          // 0..511
            const int r = c >> 2, k8 = (c & 3) * 8;
            if (A_F32) {
                const float* Af = (const float*)Av;
                const float4 f0 = *(const float4*)(Af + (size_t)(row0 + r) * K + k0 + k8);
                const float4 f1 = *(const float4*)(Af + (size_t)(row0 + r) * K + k0 + k8 + 4);
                const unsigned u0 = cvtpk_bf16(f0.x, f0.y);
                const unsigned u1 = cvtpk_bf16(f0.z, f0.w);
                const unsigned u2 = cvtpk_bf16(f1.x, f1.y);
                const unsigned u3 = cvtpk_bf16(f1.z, f1.w);
                *(short8*)(&As[c * 8]) = frag_from_u32(u0, u1, u2, u3);
            } else {
                const short* Ab = (const short*)Av;
                gload_lds16(Ab + (size_t)(row0 + r) * K + k0 + k8, As + c * 8);
            }
            gload_lds16(Bt + (size_t)(col0 + r) * K + k0 + k8, Bs + c * 8);
        }
        __syncthreads();
        short8 af[4], bfr[4];
#pragma unroll
        for (int m = 0; m < 4; ++m)
            af[m] = *(const short8*)(&As[(wr * 64 + m * 16 + lm) * 32 + lg * 8]);
#pragma unroll
        for (int n = 0; n < 4; ++n)
            bfr[n] = *(const short8*)(&Bs[(wc * 64 + n * 16 + lm) * 32 + lg * 8]);
#pragma unroll
        for (int m = 0; m < 4; ++m)
#pragma unroll
            for (int n = 0; n < 4; ++n)
                acc[m][n] = mfma16(af[m], bfr[n], acc[m][n]);
    }

    const bool vreg = (!STORE_F32) && (col0 >= nsplit);
#pragma unroll
    for (int m = 0; m < 4; ++m)
#pragma unroll
        for (int n = 0; n < 4; ++n) {
            if (vreg) {
#pragma unroll
                for (int r = 0; r < 4; ++r) {
                    const int row = row0 + wr * 64 + m * 16 + lg * 4 + r;
                    const int col = col0 + wc * 64 + n * 16 + lm - nsplit;
                    Cv[(size_t)row * 512 + col] = (short)f2bf(acc[m][n][r]);
                }
            } else {
#pragma unroll
                for (int r = 0; r < 4; ++r) {
                    const int row = row0 + wr * 64 + m * 16 + lg * 4 + r;
                    const int col = col0 + wc * 64 + n * 16 + lm;
                    const float v = acc[m][n][r];
                    if (STORE_F32) ((float*)C)[(size_t)row * ldc + col] = v;
                    else ((unsigned short*)C)[(size_t)row * ldc + col] = f2bf(v);
                }
            }
        }
}

// ---------------- MFMA flash attention (causal, GQA 4:1), 32x32x16 ----------------
// grid (8, 32, 2): block handles BOTH q-tiles {bx, 15-bx} sequentially -> every
// block does exactly 34 kv-tiles (perfect balance). 256 threads = 4 waves; wave w
// owns q rows [qt*128 + w*32, +32). Lane: n = l&31 (its q), hi = l>>5.
// S^T = K·Q^T; softmax lane-local (exp2 domain, tree reductions, defer-rescale);
// P-frags in-register via cvt_pk + 2x permlane32_swap; O^T = V^T·P^T.
__global__ __launch_bounds__(256) void attn_fwd(const short* __restrict__ qkv,
                                                const short* __restrict__ vt,
                                                unsigned short* __restrict__ aout) {
    __shared__ short Ks[2][64 * 64];
    __shared__ short Vs[2][64 * 64];
    const int bx = blockIdx.x, h = blockIdx.y, b = blockIdx.z;
    const int g = h >> 2;
    const int tid = threadIdx.x, l = tid & 63, w = tid >> 6;
    const int n = l & 31, hi = l >> 5;

    const size_t krow_base = (size_t)(b * T_SEQ) * QKS + 2048 + g * 64;
    const size_t vrow_base = (size_t)(g * 64) * NROWS + b * T_SEQ;

    for (int sub = 0; sub < 2; ++sub) {
        const int qt = sub ? (15 - bx) : bx;
        const int qrow0w = qt * 128 + w * 32;
        const int qg = qrow0w + n;

        short8 qb[4];
        {
            const size_t qbase = (size_t)(b * T_SEQ + qg) * QKS + h * 64 + hi * 8;
            qb[0] = *(const short8*)(qkv + qbase);
            qb[1] = *(const short8*)(qkv + qbase + 16);
            qb[2] = *(const short8*)(qkv + qbase + 32);
            qb[3] = *(const short8*)(qkv + qbase + 48);
        }

        f32x16 acc0 = {}, acc1 = {};
        float m_run = -1e30f, l_run = 0.f;   // m_run in log2-scaled domain

        const int ntiles = 2 * qt + 2;

        auto STAGE = [&](int buf, int kt) {
            const int krow0 = kt * 64;
#pragma unroll
            for (int p = 0; p < 2; ++p) {
                const int c = p * 256 + tid;        // 0..511
                const int r = c >> 3, gk = c & 7;
                const int gs = gk ^ (r & 7);
                gload_lds16(qkv + krow_base + (size_t)(krow0 + r) * QKS + gs * 8,
                            &Ks[buf][c * 8]);
                gload_lds16(vt + vrow_base + (size_t)r * NROWS + krow0 + gs * 8,
                            &Vs[buf][c * 8]);
            }
        };

        STAGE(0, 0);
        asm volatile("s_waitcnt vmcnt(0)" ::: "memory");
        __syncthreads();

        for (int kt = 0; kt < ntiles; ++kt) {
            const int cur = kt & 1;
            if (kt + 1 < ntiles) STAGE(cur ^ 1, kt + 1);

            const int krow0 = kt * 64;
            const bool active = (krow0 <= qrow0w + 31);
            if (active) {
                const short* KsB = &Ks[cur][0];
                const short* VsB = &Vs[cur][0];

                // ---- S^T = K Q^T ----
                f32x16 s0 = {}, s1 = {};
                __builtin_amdgcn_s_setprio(1);
#pragma unroll
                for (int ks = 0; ks < 4; ++ks) {
                    const int perm = ((2 * ks + hi) ^ (n & 7)) * 8;
                    const short8 kf0 = *(const short8*)(KsB + n * 64 + perm);
                    const short8 kf1 = *(const short8*)(KsB + (32 + n) * 64 + perm);
                    s0 = mfma32(kf0, qb[ks], s0);
                    s1 = mfma32(kf1, qb[ks], s1);
                }
                __builtin_amdgcn_s_setprio(0);

                // ---- causal mask (raw-score domain) ----
                if (krow0 + 63 > qrow0w) {
#pragma unroll
                    for (int r = 0; r < 16; ++r) {
                        const int jj = krow0 + (r & 3) + 8 * (r >> 2) + 4 * hi;
                        if (jj > qg) s0[r] = -1e30f;
                        if (jj + 32 > qg) s1[r] = -1e30f;
                    }
                }

                // ---- tree max (depth 5) + cross-half shfl ----
                float t8[8];
#pragma unroll
                for (int r = 0; r < 8; ++r)
                    t8[r] = fmaxf(fmaxf(s0[r], s0[r + 8]), fmaxf(s1[r], s1[r + 8]));
                float mx = fmaxf(fmaxf(fmaxf(t8[0], t8[1]), fmaxf(t8[2], t8[3])),
                                 fmaxf(fmaxf(t8[4], t8[5]), fmaxf(t8[6], t8[7])));
                mx = fmaxf(mx, __shfl_xor(mx, 32));
                const float pm = mx * KC;            // log2 domain

                // ---- defer-rescale (T13): skip when max growth <= 8 ----
                if (!__all(pm <= m_run + 8.0f)) {
                    const float mn = fmaxf(m_run, pm);
                    const float sc = __builtin_amdgcn_exp2f(m_run - mn);
                    l_run *= sc;
#pragma unroll
                    for (int r = 0; r < 16; ++r) { acc0[r] *= sc; acc1[r] *= sc; }
                    m_run = mn;
                }

                // ---- P = exp2(s*KC - m_run), 4-way partial sums ----
                float ps[4] = {0.f, 0.f, 0.f, 0.f};
#pragma unroll
                for (int r = 0; r < 16; ++r) {
                    const float p = __builtin_amdgcn_exp2f(__builtin_fmaf(s0[r], KC, -m_run));
                    s0[r] = p; ps[r & 3] += p;
                }
#pragma unroll
                for (int r = 0; r < 16; ++r) {
                    const float p = __builtin_amdgcn_exp2f(__builtin_fmaf(s1[r], KC, -m_run));
                    s1[r] = p; ps[r & 3] += p;
                }
                float pst = (ps[0] + ps[1]) + (ps[2] + ps[3]);
                pst += __shfl_xor(pst, 32);
                l_run += pst;

                // ---- PV: O^T += V^T P^T (P-frags via cvt_pk + 2 permlane swaps) ----
                __builtin_amdgcn_s_setprio(1);
#define PV_STEP(KS, SV)                                                              \
                {                                                                    \
                    const unsigned c01 = cvtpk_bf16(SV[((KS)&1)*8+0], SV[((KS)&1)*8+1]); \
                    const unsigned c23 = cvtpk_bf16(SV[((KS)&1)*8+2], SV[((KS)&1)*8+3]); \
                    const unsigned c45 = cvtpk_bf16(SV[((KS)&1)*8+4], SV[((KS)&1)*8+5]); \
                    const unsigned c67 = cvtpk_bf16(SV[((KS)&1)*8+6], SV[((KS)&1)*8+7]); \
                    const i32x2 r02 = __builtin_amdgcn_permlane32_swap((int)c01, (int)c45, false, false); \
                    const i32x2 r13 = __builtin_amdgcn_permlane32_swap((int)c23, (int)c67, false, false); \
                    const short8 pfrag = frag_from_u32((unsigned)r02.x, (unsigned)r13.x,  \
                                                       (unsigned)r02.y, (unsigned)r13.y); \
                    const int permv = ((2 * (KS) + hi) ^ (n & 7)) * 8;               \
                    const short8 vf0 = *(const short8*)(VsB + n * 64 + permv);       \
                    const short8 vf1 = *(const short8*)(VsB + (32 + n) * 64 + permv);\
                    acc0 = mfma32(vf0, pfrag, acc0);                                 \
                    acc1 = mfma32(vf1, pfrag, acc1);                                 \
                }
                PV_STEP(0, s0)
                PV_STEP(1, s0)
                PV_STEP(2, s1)
                PV_STEP(3, s1)
#undef PV_STEP
                __builtin_amdgcn_s_setprio(0);
            }

            asm volatile("s_waitcnt vmcnt(0)" ::: "memory");
            __syncthreads();
        }

        // ---- epilogue: O[q][d], d = dt*32 + rg*8 + hi*4 + (0..3) ----
        const float invl = 1.0f / l_run;
        const size_t orow = (size_t)(b * T_SEQ + qg) * 2048 + h * 64;
#pragma unroll
        for (int rg = 0; rg < 4; ++rg) {
            u32x2 pk0, pk1;
            pk0.x = cvtpk_bf16(acc0[rg * 4 + 0] * invl, acc0[rg * 4 + 1] * invl);
            pk0.y = cvtpk_bf16(acc0[rg * 4 + 2] * invl, acc0[rg * 4 + 3] * invl);
            pk1.x = cvtpk_bf16(acc1[rg * 4 + 0] * invl, acc1[rg * 4 + 1] * invl);
            pk1.y = cvtpk_bf16(acc1[rg * 4 + 2] * invl, acc1[rg * 4 + 3] * invl);
            *(u32x2*)(aout + orow + rg * 8 + hi * 4) = pk0;
            *(u32x2*)(aout + orow + 32 + rg * 8 + hi * 4) = pk1;
        }
    }
}

// ---------------- launch ----------------
extern "C" void kernel_launch(void* const* d_in, const int* in_sizes, int n_in,
                              void* d_out, int out_size, void* d_ws, size_t ws_size,
                              hipStream_t stream) {
    const float* x    = (const float*)d_in[0];
    const float* fcos = (const float*)d_in[1];
    const float* fsin = (const float*)d_in[2];
    const float* wq   = (const float*)d_in[4];
    const float* wk   = (const float*)d_in[5];
    const float* wv   = (const float*)d_in[6];
    const float* wo   = (const float*)d_in[7];

    short* ws0  = (short*)d_ws;
    short* qkvb = ws0;                    // [0, 20MB): 4096 x 2560 (q|k)
    short* vt   = ws0 + 10485760;         // [20, 24MB): V^T 512 x 4096
    short* wT   = ws0 + 12582912;         // [24, 36MB): wq^T|wk^T|wv^T (3072 x 2048)
    short* vbuf = ws0 + 18874368;         // [36, 40MB): V 4096 x 512
    short* aout = ws0 + 12582912;         // [24, 40MB): attn out (after wT/vbuf dead)
    short* woT  = ws0;                    // [0, 8MB): wo^T (after qkvb dead)

    // 1. weight transposes (fp32 -> bf16, [K][N] -> [N][K])
    transpose_f32_bf16<<<dim3(64, 64), 256, 0, stream>>>(wq, wT, 2048, 2048);
    transpose_f32_bf16<<<dim3(16, 64), 256, 0, stream>>>(wk, wT + 2048 * 2048, 2048, 512);
    transpose_f32_bf16<<<dim3(16, 64), 256, 0, stream>>>(wv, wT + 2560 * 2048, 2048, 512);
    // 2. fused QKV projection: q,k -> qkvb (stride 2560); v -> vbuf (stride 512)
    gemm_mfma<1, 0><<<dim3(24, 32), 256, 0, stream>>>(x, wT, qkvb, QKS, vbuf, 2560,
                                                      NROWS, 3072, 2048);
    // 3. RoPE on q and k
    rope_kernel<<<16384, 256, 0, stream>>>((unsigned short*)qkvb, fcos, fsin, 32, QKS, 0);
    rope_kernel<<<4096, 256, 0, stream>>>((unsigned short*)qkvb, fcos, fsin, 8, QKS, 2048);
    // 4. V -> V^T
    transpose_bf16<<<dim3(16, 128), 256, 0, stream>>>(vbuf, vt, NROWS, 512);
    // 5. attention (paired q-tiles for perfect load balance)
    attn_fwd<<<dim3(8, 32, 2), 256, 0, stream>>>(qkvb, vt, (unsigned short*)aout);
    // 6. wo^T (qkvb region dead now)
    transpose_f32_bf16<<<dim3(64, 64), 256, 0, stream>>>(wo, woT, 2048, 2048);
    // 7. output projection
    gemm_mfma<0, 1><<<dim3(16, 32), 256, 0, stream>>>(aout, woT, d_out, 2048, nullptr, 1 << 30,
                                                      NROWS, 2048, 2048);
}

// Round 6
// 234.544 us; speedup vs baseline: 16.7543x; 1.0435x over previous
//
#include <hip/hip_runtime.h>
#include <hip/hip_bf16.h>

#define T_SEQ 2048
#define NROWS 4096     // B*T
#define QKS   2560     // qkv buffer row stride: q(2048) + k(512)

typedef __attribute__((ext_vector_type(8))) short short8;
typedef __attribute__((ext_vector_type(4))) float f32x4;
typedef __attribute__((ext_vector_type(16))) float f32x16;
typedef __attribute__((ext_vector_type(2))) int i32x2;
typedef __attribute__((ext_vector_type(2))) unsigned int u32x2;

#define KC 0.18033688f   // 0.125 * log2(e)

__device__ __forceinline__ unsigned short f2bf(float f) {
    unsigned u = __builtin_bit_cast(unsigned, f);
    u += 0x7FFF + ((u >> 16) & 1);
    return (unsigned short)(u >> 16);
}
__device__ __forceinline__ float bf2f(unsigned short s) {
    unsigned u = ((unsigned)s) << 16;
    return __builtin_bit_cast(float, u);
}

__device__ __forceinline__ void gload_lds16(const void* g, void* l) {
    __builtin_amdgcn_global_load_lds(
        (const __attribute__((address_space(1))) unsigned int*)g,
        (__attribute__((address_space(3))) unsigned int*)l,
        16, 0, 0);
}

__device__ __forceinline__ f32x4 mfma16(short8 a, short8 b, f32x4 c) {
    return __builtin_amdgcn_mfma_f32_16x16x32_bf16(a, b, c, 0, 0, 0);
}
__device__ __forceinline__ f32x16 mfma32(short8 a, short8 b, f32x16 c) {
    return __builtin_amdgcn_mfma_f32_32x32x16_bf16(a, b, c, 0, 0, 0);
}

__device__ __forceinline__ unsigned cvtpk_bf16(float lo, float hi) {
    unsigned r;
    asm("v_cvt_pk_bf16_f32 %0, %1, %2" : "=v"(r) : "v"(lo), "v"(hi));
    return r;
}

__device__ __forceinline__ short8 frag_from_u32(unsigned w0, unsigned w1, unsigned w2, unsigned w3) {
    union { unsigned u[4]; short8 s; } t;
    t.u[0] = w0; t.u[1] = w1; t.u[2] = w2; t.u[3] = w3;
    return t.s;
}

// ---------------- fp32 -> bf16 convert (8 elems/thread, exact-size grid) ----------------
__global__ __launch_bounds__(256) void conv_f32_bf16(const float* __restrict__ S,
                                                     short* __restrict__ D) {
    const int i = blockIdx.x * 256 + threadIdx.x;
    const float4 a = ((const float4*)S)[i * 2];
    const float4 b = ((const float4*)S)[i * 2 + 1];
    ((short8*)D)[i] = frag_from_u32(cvtpk_bf16(a.x, a.y), cvtpk_bf16(a.z, a.w),
                                    cvtpk_bf16(b.x, b.y), cvtpk_bf16(b.z, b.w));
}

// ---------------- fused wq/wk/wv transpose: fp32[K][N] -> bf16 wT[N'][K] ----------------
// grid (96, 64): bx<64 -> wq (N=2048), 64..79 -> wk, 80..95 -> wv (N=512). K=2048.
__global__ __launch_bounds__(256) void trans_wqkv(const float* __restrict__ wq,
                                                  const float* __restrict__ wk,
                                                  const float* __restrict__ wv,
                                                  short* __restrict__ wT) {
    __shared__ float tile[32][33];
    const int bx = blockIdx.x, by = blockIdx.y;
    const float* S; int srcN, nt, dstRow0;
    if (bx < 64)      { S = wq; srcN = 2048; nt = bx;      dstRow0 = 0;    }
    else if (bx < 80) { S = wk; srcN = 512;  nt = bx - 64; dstRow0 = 2048; }
    else              { S = wv; srcN = 512;  nt = bx - 80; dstRow0 = 2560; }
    const int n0 = nt * 32, k0 = by * 32;
    const int t = threadIdx.x;
#pragma unroll
    for (int j = 0; j < 4; ++j) {
        int lin = t + 256 * j;
        int kk = lin >> 5, nn = lin & 31;
        tile[kk][nn] = S[(size_t)(k0 + kk) * srcN + n0 + nn];
    }
    __syncthreads();
#pragma unroll
    for (int j = 0; j < 4; ++j) {
        int lin = t + 256 * j;
        int nn = lin >> 5, kk = lin & 31;
        wT[(size_t)(dstRow0 + n0 + nn) * 2048 + k0 + kk] = (short)f2bf(tile[kk][nn]);
    }
}

// ---------------- single-source transpose fp32[K][N] -> bf16[N][K] (wo) ----------------
__global__ __launch_bounds__(256) void transpose_f32_bf16(const float* __restrict__ S,
                                                          short* __restrict__ D,
                                                          int K, int N) {
    __shared__ float tile[32][33];
    const int n0 = blockIdx.x * 32, k0 = blockIdx.y * 32;
    const int t = threadIdx.x;
#pragma unroll
    for (int j = 0; j < 4; ++j) {
        int lin = t + 256 * j;
        int kk = lin >> 5, nn = lin & 31;
        tile[kk][nn] = S[(size_t)(k0 + kk) * N + n0 + nn];
    }
    __syncthreads();
#pragma unroll
    for (int j = 0; j < 4; ++j) {
        int lin = t + 256 * j;
        int nn = lin >> 5, kk = lin & 31;
        D[(size_t)(n0 + nn) * K + k0 + kk] = (short)f2bf(tile[kk][nn]);
    }
}

// ---------------- transpose bf16[R][C] -> bf16[C][R] ----------------
__global__ __launch_bounds__(256) void transpose_bf16(const short* __restrict__ S,
                                                      short* __restrict__ D,
                                                      int R, int Cc) {
    __shared__ short tile[32][33];
    const int c0 = blockIdx.x * 32, r0 = blockIdx.y * 32;
    const int t = threadIdx.x;
#pragma unroll
    for (int j = 0; j < 4; ++j) {
        int lin = t + 256 * j;
        int rr = lin >> 5, cc = lin & 31;
        tile[rr][cc] = S[(size_t)(r0 + rr) * Cc + c0 + cc];
    }
    __syncthreads();
#pragma unroll
    for (int j = 0; j < 4; ++j) {
        int lin = t + 256 * j;
        int cc = lin >> 5, rr = lin & 31;
        D[(size_t)(c0 + cc) * R + r0 + rr] = tile[rr][cc];
    }
}

// ---------------- fused RoPE over q and k regions of qkvb ----------------
// idx < 4194304 -> q (Hn=32, c0=0); else k (Hn=8, c0=2048). Stride QKS.
__global__ __launch_bounds__(256) void rope_fused(unsigned short* __restrict__ t,
                                                  const float* __restrict__ cosp,
                                                  const float* __restrict__ sinp) {
    int idx = blockIdx.x * 256 + threadIdx.x;
    int Hn = 32, c0 = 0;
    if (idx >= 4194304) { idx -= 4194304; Hn = 8; c0 = 2048; }
    const int p = idx & 31;
    const int hh = (idx >> 5) % Hn;
    const int row = idx / (32 * Hn);
    const int tpos = row & (T_SEQ - 1);
    const float c = cosp[tpos * 32 + p];
    const float s = sinp[tpos * 32 + p];
    const size_t base = (size_t)row * QKS + c0 + hh * 64 + 2 * p;
    float e = bf2f(t[base]), o = bf2f(t[base + 1]);
    t[base]     = f2bf(e * c - o * s);
    t[base + 1] = f2bf(e * s + o * c);
}

// ---------------- MFMA GEMM: C[M,N] = A[M,K] @ Bt[N,K]^T ----------------
// m97 structure: 128x128 tile, BK=32, 4 waves (2x2), linear LDS, dual gload_lds.
// XCD-aware bijective block swizzle (requires nwg % 8 == 0).
// cols >= nsplit go (bf16) to Cv with row stride 512 at col-nsplit.
template <int STORE_F32>
__global__ __launch_bounds__(256) void gemm_mfma(const short* __restrict__ A,
                                                 const short* __restrict__ Bt,
                                                 void* __restrict__ C, int ldc,
                                                 short* __restrict__ Cv, int nsplit,
                                                 int M, int N, int K) {
    __shared__ short As[128 * 32];
    __shared__ short Bs[128 * 32];
    const int tid = threadIdx.x;
    const int l = tid & 63, w = tid >> 6;
    const int wr = w >> 1, wc = w & 1;
    const int lm = l & 15, lg = l >> 4;

    // XCD swizzle: contiguous tile chunk per XCD
    const int nwg = gridDim.x * gridDim.y;
    int bid = blockIdx.y * gridDim.x + blockIdx.x;
    bid = (bid & 7) * (nwg >> 3) + (bid >> 3);
    const int row0 = (bid / gridDim.x) * 128;
    const int col0 = (bid % gridDim.x) * 128;

    f32x4 acc[4][4];
#pragma unroll
    for (int m = 0; m < 4; ++m)
#pragma unroll
        for (int n = 0; n < 4; ++n) acc[m][n] = (f32x4){0.f, 0.f, 0.f, 0.f};

    for (int k0 = 0; k0 < K; k0 += 32) {
        __syncthreads();
#pragma unroll
        for (int p = 0; p < 2; ++p) {
            const int c = tid + 256 * p;          // 0..511
            const int r = c >> 2, k8 = (c & 3) * 8;
            gload_lds16(A  + (size_t)(row0 + r) * K + k0 + k8, As + c * 8);
            gload_lds16(Bt + (size_t)(col0 + r) * K + k0 + k8, Bs + c * 8);
        }
        __syncthreads();
        short8 af[4], bfr[4];
#pragma unroll
        for (int m = 0; m < 4; ++m)
            af[m] = *(const short8*)(&As[(wr * 64 + m * 16 + lm) * 32 + lg * 8]);
#pragma unroll
        for (int n = 0; n < 4; ++n)
            bfr[n] = *(const short8*)(&Bs[(wc * 64 + n * 16 + lm) * 32 + lg * 8]);
#pragma unroll
        for (int m = 0; m < 4; ++m)
#pragma unroll
            for (int n = 0; n < 4; ++n)
                acc[m][n] = mfma16(af[m], bfr[n], acc[m][n]);
    }

    const bool vreg = (!STORE_F32) && (col0 >= nsplit);
#pragma unroll
    for (int m = 0; m < 4; ++m)
#pragma unroll
        for (int n = 0; n < 4; ++n) {
            if (vreg) {
#pragma unroll
                for (int r = 0; r < 4; ++r) {
                    const int row = row0 + wr * 64 + m * 16 + lg * 4 + r;
                    const int col = col0 + wc * 64 + n * 16 + lm - nsplit;
                    Cv[(size_t)row * 512 + col] = (short)f2bf(acc[m][n][r]);
                }
            } else {
#pragma unroll
                for (int r = 0; r < 4; ++r) {
                    const int row = row0 + wr * 64 + m * 16 + lg * 4 + r;
                    const int col = col0 + wc * 64 + n * 16 + lm;
                    const float v = acc[m][n][r];
                    if (STORE_F32) ((float*)C)[(size_t)row * ldc + col] = v;
                    else ((unsigned short*)C)[(size_t)row * ldc + col] = f2bf(v);
                }
            }
        }
}

// ---------------- MFMA flash attention (causal, GQA 4:1), 32x32x16 ----------------
// grid (8, 32, 2): block handles BOTH q-tiles {bx, 15-bx} -> exactly 34 kv-tiles each.
// 256 threads = 4 waves; wave w owns q rows [qt*128 + w*32, +32). n = l&31, hi = l>>5.
// S^T = K·Q^T; lane-local softmax (exp2 domain, tree reductions, defer-rescale);
// P-frags in-register via cvt_pk + 2x permlane32_swap; O^T = V^T·P^T.
__global__ __launch_bounds__(256) void attn_fwd(const short* __restrict__ qkv,
                                                const short* __restrict__ vt,
                                                unsigned short* __restrict__ aout) {
    __shared__ short Ks[2][64 * 64];
    __shared__ short Vs[2][64 * 64];
    const int bx = blockIdx.x, h = blockIdx.y, b = blockIdx.z;
    const int g = h >> 2;
    const int tid = threadIdx.x, l = tid & 63, w = tid >> 6;
    const int n = l & 31, hi = l >> 5;

    const size_t krow_base = (size_t)(b * T_SEQ) * QKS + 2048 + g * 64;
    const size_t vrow_base = (size_t)(g * 64) * NROWS + b * T_SEQ;

    for (int sub = 0; sub < 2; ++sub) {
        const int qt = sub ? (15 - bx) : bx;
        const int qrow0w = qt * 128 + w * 32;
        const int qg = qrow0w + n;

        short8 qb[4];
        {
            const size_t qbase = (size_t)(b * T_SEQ + qg) * QKS + h * 64 + hi * 8;
            qb[0] = *(const short8*)(qkv + qbase);
            qb[1] = *(const short8*)(qkv + qbase + 16);
            qb[2] = *(const short8*)(qkv + qbase + 32);
            qb[3] = *(const short8*)(qkv + qbase + 48);
        }

        f32x16 acc0 = {}, acc1 = {};
        float m_run = -1e30f, l_run = 0.f;   // m_run in log2-scaled domain

        const int ntiles = 2 * qt + 2;

        auto STAGE = [&](int buf, int kt) {
            const int krow0 = kt * 64;
#pragma unroll
            for (int p = 0; p < 2; ++p) {
                const int c = p * 256 + tid;        // 0..511
                const int r = c >> 3, gk = c & 7;
                const int gs = gk ^ (r & 7);
                gload_lds16(qkv + krow_base + (size_t)(krow0 + r) * QKS + gs * 8,
                            &Ks[buf][c * 8]);
                gload_lds16(vt + vrow_base + (size_t)r * NROWS + krow0 + gs * 8,
                            &Vs[buf][c * 8]);
            }
        };

        STAGE(0, 0);
        asm volatile("s_waitcnt vmcnt(0)" ::: "memory");
        __syncthreads();

        for (int kt = 0; kt < ntiles; ++kt) {
            const int cur = kt & 1;
            if (kt + 1 < ntiles) STAGE(cur ^ 1, kt + 1);

            const int krow0 = kt * 64;
            const bool active = (krow0 <= qrow0w + 31);
            if (active) {
                const short* KsB = &Ks[cur][0];
                const short* VsB = &Vs[cur][0];

                // ---- S^T = K Q^T ----
                f32x16 s0 = {}, s1 = {};
                __builtin_amdgcn_s_setprio(1);
#pragma unroll
                for (int ks = 0; ks < 4; ++ks) {
                    const int perm = ((2 * ks + hi) ^ (n & 7)) * 8;
                    const short8 kf0 = *(const short8*)(KsB + n * 64 + perm);
                    const short8 kf1 = *(const short8*)(KsB + (32 + n) * 64 + perm);
                    s0 = mfma32(kf0, qb[ks], s0);
                    s1 = mfma32(kf1, qb[ks], s1);
                }
                __builtin_amdgcn_s_setprio(0);

                // ---- causal mask (raw-score domain) ----
                if (krow0 + 63 > qrow0w) {
#pragma unroll
                    for (int r = 0; r < 16; ++r) {
                        const int jj = krow0 + (r & 3) + 8 * (r >> 2) + 4 * hi;
                        if (jj > qg) s0[r] = -1e30f;
                        if (jj + 32 > qg) s1[r] = -1e30f;
                    }
                }

                // ---- tree max (depth 5) + cross-half shfl ----
                float t8[8];
#pragma unroll
                for (int r = 0; r < 8; ++r)
                    t8[r] = fmaxf(fmaxf(s0[r], s0[r + 8]), fmaxf(s1[r], s1[r + 8]));
                float mx = fmaxf(fmaxf(fmaxf(t8[0], t8[1]), fmaxf(t8[2], t8[3])),
                                 fmaxf(fmaxf(t8[4], t8[5]), fmaxf(t8[6], t8[7])));
                mx = fmaxf(mx, __shfl_xor(mx, 32));
                const float pm = mx * KC;            // log2 domain

                // ---- defer-rescale (T13): skip when max growth <= 8 ----
                if (!__all(pm <= m_run + 8.0f)) {
                    const float mn = fmaxf(m_run, pm);
                    const float sc = __builtin_amdgcn_exp2f(m_run - mn);
                    l_run *= sc;
#pragma unroll
                    for (int r = 0; r < 16; ++r) { acc0[r] *= sc; acc1[r] *= sc; }
                    m_run = mn;
                }

                // ---- P = exp2(s*KC - m_run), 4-way partial sums ----
                float ps[4] = {0.f, 0.f, 0.f, 0.f};
#pragma unroll
                for (int r = 0; r < 16; ++r) {
                    const float p = __builtin_amdgcn_exp2f(__builtin_fmaf(s0[r], KC, -m_run));
                    s0[r] = p; ps[r & 3] += p;
                }
#pragma unroll
                for (int r = 0; r < 16; ++r) {
                    const float p = __builtin_amdgcn_exp2f(__builtin_fmaf(s1[r], KC, -m_run));
                    s1[r] = p; ps[r & 3] += p;
                }
                float pst = (ps[0] + ps[1]) + (ps[2] + ps[3]);
                pst += __shfl_xor(pst, 32);
                l_run += pst;

                // ---- PV: O^T += V^T P^T (P-frags via cvt_pk + 2 permlane swaps) ----
                __builtin_amdgcn_s_setprio(1);
#define PV_STEP(KS, SV)                                                              \
                {                                                                    \
                    const unsigned c01 = cvtpk_bf16(SV[((KS)&1)*8+0], SV[((KS)&1)*8+1]); \
                    const unsigned c23 = cvtpk_bf16(SV[((KS)&1)*8+2], SV[((KS)&1)*8+3]); \
                    const unsigned c45 = cvtpk_bf16(SV[((KS)&1)*8+4], SV[((KS)&1)*8+5]); \
                    const unsigned c67 = cvtpk_bf16(SV[((KS)&1)*8+6], SV[((KS)&1)*8+7]); \
                    const i32x2 r02 = __builtin_amdgcn_permlane32_swap((int)c01, (int)c45, false, false); \
                    const i32x2 r13 = __builtin_amdgcn_permlane32_swap((int)c23, (int)c67, false, false); \
                    const short8 pfrag = frag_from_u32((unsigned)r02.x, (unsigned)r13.x,  \
                                                       (unsigned)r02.y, (unsigned)r13.y); \
                    const int permv = ((2 * (KS) + hi) ^ (n & 7)) * 8;               \
                    const short8 vf0 = *(const short8*)(VsB + n * 64 + permv);       \
                    const short8 vf1 = *(const short8*)(VsB + (32 + n) * 64 + permv);\
                    acc0 = mfma32(vf0, pfrag, acc0);                                 \
                    acc1 = mfma32(vf1, pfrag, acc1);                                 \
                }
                PV_STEP(0, s0)
                PV_STEP(1, s0)
                PV_STEP(2, s1)
                PV_STEP(3, s1)
#undef PV_STEP
                __builtin_amdgcn_s_setprio(0);
            }

            asm volatile("s_waitcnt vmcnt(0)" ::: "memory");
            __syncthreads();
        }

        // ---- epilogue: O[q][d], d = dt*32 + rg*8 + hi*4 + (0..3) ----
        const float invl = 1.0f / l_run;
        const size_t orow = (size_t)(b * T_SEQ + qg) * 2048 + h * 64;
#pragma unroll
        for (int rg = 0; rg < 4; ++rg) {
            u32x2 pk0, pk1;
            pk0.x = cvtpk_bf16(acc0[rg * 4 + 0] * invl, acc0[rg * 4 + 1] * invl);
            pk0.y = cvtpk_bf16(acc0[rg * 4 + 2] * invl, acc0[rg * 4 + 3] * invl);
            pk1.x = cvtpk_bf16(acc1[rg * 4 + 0] * invl, acc1[rg * 4 + 1] * invl);
            pk1.y = cvtpk_bf16(acc1[rg * 4 + 2] * invl, acc1[rg * 4 + 3] * invl);
            *(u32x2*)(aout + orow + rg * 8 + hi * 4) = pk0;
            *(u32x2*)(aout + orow + 32 + rg * 8 + hi * 4) = pk1;
        }
    }
}

// ---------------- launch ----------------
extern "C" void kernel_launch(void* const* d_in, const int* in_sizes, int n_in,
                              void* d_out, int out_size, void* d_ws, size_t ws_size,
                              hipStream_t stream) {
    const float* x    = (const float*)d_in[0];
    const float* fcos = (const float*)d_in[1];
    const float* fsin = (const float*)d_in[2];
    const float* wq   = (const float*)d_in[4];
    const float* wk   = (const float*)d_in[5];
    const float* wv   = (const float*)d_in[6];
    const float* wo   = (const float*)d_in[7];

    short* ws0  = (short*)d_ws;
    short* qkvb = ws0;                    // [0, 20MB): 4096 x 2560 (q|k)
    short* vt   = ws0 + 10485760;         // [20, 24MB): V^T 512 x 4096
    short* wT   = ws0 + 12582912;         // [24, 36MB): wq^T|wk^T|wv^T (3072 x 2048)
    short* vbuf = ws0 + 18874368;         // [36, 40MB): V 4096 x 512
    short* aout = ws0 + 12582912;         // [24, 40MB): attn out (after wT/vbuf dead)
    short* woT  = ws0;                    // [0, 8MB): wo^T (after qkvb dead)
    short* xb   = (short*)d_out;          // x as bf16 lives in d_out until GEMM2 rewrites it

    // 1. x -> bf16 (into d_out scratch)
    conv_f32_bf16<<<4096, 256, 0, stream>>>(x, xb);
    // 2. fused weight transposes (wq|wk|wv -> wT)
    trans_wqkv<<<dim3(96, 64), 256, 0, stream>>>(wq, wk, wv, wT);
    // 3. fused QKV projection: q,k -> qkvb (stride 2560); v -> vbuf (stride 512)
    gemm_mfma<0><<<dim3(24, 32), 256, 0, stream>>>(xb, wT, qkvb, QKS, vbuf, 2560,
                                                   NROWS, 3072, 2048);
    // 4. fused RoPE on q and k
    rope_fused<<<20480, 256, 0, stream>>>((unsigned short*)qkvb, fcos, fsin);
    // 5. V -> V^T
    transpose_bf16<<<dim3(16, 128), 256, 0, stream>>>(vbuf, vt, NROWS, 512);
    // 6. attention (paired q-tiles for perfect load balance)
    attn_fwd<<<dim3(8, 32, 2), 256, 0, stream>>>(qkvb, vt, (unsigned short*)aout);
    // 7. wo^T (qkvb region dead now)
    transpose_f32_bf16<<<dim3(64, 64), 256, 0, stream>>>(wo, woT, 2048, 2048);
    // 8. output projection (xb in d_out is dead; GEMM2 overwrites all of d_out)
    gemm_mfma<1><<<dim3(16, 32), 256, 0, stream>>>(aout, woT, d_out, 2048, nullptr, 1 << 30,
                                                   NROWS, 2048, 2048);
}

// Round 7
// 231.255 us; speedup vs baseline: 16.9926x; 1.0142x over previous
//
#include <hip/hip_runtime.h>
#include <hip/hip_bf16.h>

#define T_SEQ 2048
#define NROWS 4096     // B*T
#define QKS   2560     // qkv buffer row stride: q(2048) + k(512)

typedef __attribute__((ext_vector_type(8))) short short8;
typedef __attribute__((ext_vector_type(4))) float f32x4;
typedef __attribute__((ext_vector_type(16))) float f32x16;
typedef __attribute__((ext_vector_type(2))) int i32x2;
typedef __attribute__((ext_vector_type(2))) unsigned int u32x2;

#define KC 0.18033688f   // 0.125 * log2(e)

__device__ __forceinline__ unsigned short f2bf(float f) {
    unsigned u = __builtin_bit_cast(unsigned, f);
    u += 0x7FFF + ((u >> 16) & 1);
    return (unsigned short)(u >> 16);
}
__device__ __forceinline__ float bf2f(unsigned short s) {
    unsigned u = ((unsigned)s) << 16;
    return __builtin_bit_cast(float, u);
}

__device__ __forceinline__ void gload_lds16(const void* g, void* l) {
    __builtin_amdgcn_global_load_lds(
        (const __attribute__((address_space(1))) unsigned int*)g,
        (__attribute__((address_space(3))) unsigned int*)l,
        16, 0, 0);
}

__device__ __forceinline__ f32x4 mfma16(short8 a, short8 b, f32x4 c) {
    return __builtin_amdgcn_mfma_f32_16x16x32_bf16(a, b, c, 0, 0, 0);
}
__device__ __forceinline__ f32x16 mfma32(short8 a, short8 b, f32x16 c) {
    return __builtin_amdgcn_mfma_f32_32x32x16_bf16(a, b, c, 0, 0, 0);
}

__device__ __forceinline__ unsigned cvtpk_bf16(float lo, float hi) {
    unsigned r;
    asm("v_cvt_pk_bf16_f32 %0, %1, %2" : "=v"(r) : "v"(lo), "v"(hi));
    return r;
}

__device__ __forceinline__ short8 frag_from_u32(unsigned w0, unsigned w1, unsigned w2, unsigned w3) {
    union { unsigned u[4]; short8 s; } t;
    t.u[0] = w0; t.u[1] = w1; t.u[2] = w2; t.u[3] = w3;
    return t.s;
}

// ---------------- fp32 -> bf16 convert (8 elems/thread, exact-size grid) ----------------
__global__ __launch_bounds__(256) void conv_f32_bf16(const float* __restrict__ S,
                                                     short* __restrict__ D) {
    const int i = blockIdx.x * 256 + threadIdx.x;
    const float4 a = ((const float4*)S)[i * 2];
    const float4 b = ((const float4*)S)[i * 2 + 1];
    ((short8*)D)[i] = frag_from_u32(cvtpk_bf16(a.x, a.y), cvtpk_bf16(a.z, a.w),
                                    cvtpk_bf16(b.x, b.y), cvtpk_bf16(b.z, b.w));
}

// ---------------- fused wq/wk/wv transpose: fp32[K][N] -> bf16 wT[N'][K] ----------------
// grid (96, 64): bx<64 -> wq (N=2048), 64..79 -> wk, 80..95 -> wv (N=512). K=2048.
__global__ __launch_bounds__(256) void trans_wqkv(const float* __restrict__ wq,
                                                  const float* __restrict__ wk,
                                                  const float* __restrict__ wv,
                                                  short* __restrict__ wT) {
    __shared__ float tile[32][33];
    const int bx = blockIdx.x, by = blockIdx.y;
    const float* S; int srcN, nt, dstRow0;
    if (bx < 64)      { S = wq; srcN = 2048; nt = bx;      dstRow0 = 0;    }
    else if (bx < 80) { S = wk; srcN = 512;  nt = bx - 64; dstRow0 = 2048; }
    else              { S = wv; srcN = 512;  nt = bx - 80; dstRow0 = 2560; }
    const int n0 = nt * 32, k0 = by * 32;
    const int t = threadIdx.x;
#pragma unroll
    for (int j = 0; j < 4; ++j) {
        int lin = t + 256 * j;
        int kk = lin >> 5, nn = lin & 31;
        tile[kk][nn] = S[(size_t)(k0 + kk) * srcN + n0 + nn];
    }
    __syncthreads();
#pragma unroll
    for (int j = 0; j < 4; ++j) {
        int lin = t + 256 * j;
        int nn = lin >> 5, kk = lin & 31;
        wT[(size_t)(dstRow0 + n0 + nn) * 2048 + k0 + kk] = (short)f2bf(tile[kk][nn]);
    }
}

// ---------------- single-source transpose fp32[K][N] -> bf16[N][K] (wo) ----------------
__global__ __launch_bounds__(256) void transpose_f32_bf16(const float* __restrict__ S,
                                                          short* __restrict__ D,
                                                          int K, int N) {
    __shared__ float tile[32][33];
    const int n0 = blockIdx.x * 32, k0 = blockIdx.y * 32;
    const int t = threadIdx.x;
#pragma unroll
    for (int j = 0; j < 4; ++j) {
        int lin = t + 256 * j;
        int kk = lin >> 5, nn = lin & 31;
        tile[kk][nn] = S[(size_t)(k0 + kk) * N + n0 + nn];
    }
    __syncthreads();
#pragma unroll
    for (int j = 0; j < 4; ++j) {
        int lin = t + 256 * j;
        int nn = lin >> 5, kk = lin & 31;
        D[(size_t)(n0 + nn) * K + k0 + kk] = (short)f2bf(tile[kk][nn]);
    }
}

// ---------------- transpose bf16[R][C] -> bf16[C][R] ----------------
__global__ __launch_bounds__(256) void transpose_bf16(const short* __restrict__ S,
                                                      short* __restrict__ D,
                                                      int R, int Cc) {
    __shared__ short tile[32][33];
    const int c0 = blockIdx.x * 32, r0 = blockIdx.y * 32;
    const int t = threadIdx.x;
#pragma unroll
    for (int j = 0; j < 4; ++j) {
        int lin = t + 256 * j;
        int rr = lin >> 5, cc = lin & 31;
        tile[rr][cc] = S[(size_t)(r0 + rr) * Cc + c0 + cc];
    }
    __syncthreads();
#pragma unroll
    for (int j = 0; j < 4; ++j) {
        int lin = t + 256 * j;
        int cc = lin >> 5, rr = lin & 31;
        D[(size_t)(c0 + cc) * R + r0 + rr] = tile[rr][cc];
    }
}

// ---------------- fused RoPE over q and k regions of qkvb ----------------
// idx < 4194304 -> q (Hn=32, c0=0); else k (Hn=8, c0=2048). Stride QKS.
__global__ __launch_bounds__(256) void rope_fused(unsigned short* __restrict__ t,
                                                  const float* __restrict__ cosp,
                                                  const float* __restrict__ sinp) {
    int idx = blockIdx.x * 256 + threadIdx.x;
    int Hn = 32, c0 = 0;
    if (idx >= 4194304) { idx -= 4194304; Hn = 8; c0 = 2048; }
    const int p = idx & 31;
    const int hh = (idx >> 5) % Hn;
    const int row = idx / (32 * Hn);
    const int tpos = row & (T_SEQ - 1);
    const float c = cosp[tpos * 32 + p];
    const float s = sinp[tpos * 32 + p];
    const size_t base = (size_t)row * QKS + c0 + hh * 64 + 2 * p;
    float e = bf2f(t[base]), o = bf2f(t[base + 1]);
    t[base]     = f2bf(e * c - o * s);
    t[base + 1] = f2bf(e * s + o * c);
}

// ---------------- MFMA GEMM: C[M,N] = A[M,K] @ Bt[N,K]^T ----------------
// m97 structure: 128x128 tile, BK=32, 4 waves (2x2), linear LDS, dual gload_lds.
// XCD-aware bijective block swizzle (requires nwg % 8 == 0).
// cols >= nsplit go (bf16) to Cv with row stride 512 at col-nsplit.
template <int STORE_F32>
__global__ __launch_bounds__(256) void gemm_mfma(const short* __restrict__ A,
                                                 const short* __restrict__ Bt,
                                                 void* __restrict__ C, int ldc,
                                                 short* __restrict__ Cv, int nsplit,
                                                 int M, int N, int K) {
    __shared__ short As[128 * 32];
    __shared__ short Bs[128 * 32];
    const int tid = threadIdx.x;
    const int l = tid & 63, w = tid >> 6;
    const int wr = w >> 1, wc = w & 1;
    const int lm = l & 15, lg = l >> 4;

    // XCD swizzle: contiguous tile chunk per XCD
    const int nwg = gridDim.x * gridDim.y;
    int bid = blockIdx.y * gridDim.x + blockIdx.x;
    bid = (bid & 7) * (nwg >> 3) + (bid >> 3);
    const int row0 = (bid / gridDim.x) * 128;
    const int col0 = (bid % gridDim.x) * 128;

    f32x4 acc[4][4];
#pragma unroll
    for (int m = 0; m < 4; ++m)
#pragma unroll
        for (int n = 0; n < 4; ++n) acc[m][n] = (f32x4){0.f, 0.f, 0.f, 0.f};

    for (int k0 = 0; k0 < K; k0 += 32) {
        __syncthreads();
#pragma unroll
        for (int p = 0; p < 2; ++p) {
            const int c = tid + 256 * p;          // 0..511
            const int r = c >> 2, k8 = (c & 3) * 8;
            gload_lds16(A  + (size_t)(row0 + r) * K + k0 + k8, As + c * 8);
            gload_lds16(Bt + (size_t)(col0 + r) * K + k0 + k8, Bs + c * 8);
        }
        __syncthreads();
        short8 af[4], bfr[4];
#pragma unroll
        for (int m = 0; m < 4; ++m)
            af[m] = *(const short8*)(&As[(wr * 64 + m * 16 + lm) * 32 + lg * 8]);
#pragma unroll
        for (int n = 0; n < 4; ++n)
            bfr[n] = *(const short8*)(&Bs[(wc * 64 + n * 16 + lm) * 32 + lg * 8]);
#pragma unroll
        for (int m = 0; m < 4; ++m)
#pragma unroll
            for (int n = 0; n < 4; ++n)
                acc[m][n] = mfma16(af[m], bfr[n], acc[m][n]);
    }

    const bool vreg = (!STORE_F32) && (col0 >= nsplit);
#pragma unroll
    for (int m = 0; m < 4; ++m)
#pragma unroll
        for (int n = 0; n < 4; ++n) {
            if (vreg) {
#pragma unroll
                for (int r = 0; r < 4; ++r) {
                    const int row = row0 + wr * 64 + m * 16 + lg * 4 + r;
                    const int col = col0 + wc * 64 + n * 16 + lm - nsplit;
                    Cv[(size_t)row * 512 + col] = (short)f2bf(acc[m][n][r]);
                }
            } else {
#pragma unroll
                for (int r = 0; r < 4; ++r) {
                    const int row = row0 + wr * 64 + m * 16 + lg * 4 + r;
                    const int col = col0 + wc * 64 + n * 16 + lm;
                    const float v = acc[m][n][r];
                    if (STORE_F32) ((float*)C)[(size_t)row * ldc + col] = v;
                    else ((unsigned short*)C)[(size_t)row * ldc + col] = f2bf(v);
                }
            }
        }
}

// ---------------- MFMA flash attention (causal, GQA 4:1), 32x32x16 ----------------
// grid (1024): block = one 32-row q-subtile x all 4 heads of one KV group.
// 4 waves = 4 heads (share K/V staging exactly); wave q rows [qt*32, +32).
// bid -> (qt, g, b) via quadrant-XOR mapping: per-CU qt-sum is constant (126)
// for BOTH contiguous x4 and stride-256 XCD round-robin block->CU assignment.
// S^T = K.Q^T; lane-local softmax (exp2, tree, defer-rescale); P-frags via
// cvt_pk + 2x permlane32_swap; O^T = V^T.P^T. n = l&31 (q), hi = l>>5.
__global__ __launch_bounds__(256, 4) void attn_fwd(const short* __restrict__ qkv,
                                                   const short* __restrict__ vt,
                                                   unsigned short* __restrict__ aout) {
    __shared__ short Ks[2][64 * 64];
    __shared__ short Vs[2][64 * 64];
    const int bid = blockIdx.x;
    const int q2 = (bid & 3) ^ ((bid >> 8) & 3);
    const int t  = (bid >> 2) & 15;
    const int gb = ((bid >> 6) & 3) | (((bid >> 8) & 3) << 2);
    const int qt = (q2 == 0) ? t : (q2 == 1) ? (31 - t) : (q2 == 2) ? (32 + t) : (63 - t);
    const int g = gb & 7, b = gb >> 3;

    const int tid = threadIdx.x, l = tid & 63, w = tid >> 6;
    const int n = l & 31, hi = l >> 5;
    const int h = g * 4 + w;            // each wave: its own head of this KV group
    const int Q0 = qt * 32;
    const int qg = Q0 + n;

    const size_t krow_base = (size_t)(b * T_SEQ) * QKS + 2048 + g * 64;
    const size_t vrow_base = (size_t)(g * 64) * NROWS + b * T_SEQ;

    short8 qb[4];
    {
        const size_t qbase = (size_t)(b * T_SEQ + qg) * QKS + h * 64 + hi * 8;
        qb[0] = *(const short8*)(qkv + qbase);
        qb[1] = *(const short8*)(qkv + qbase + 16);
        qb[2] = *(const short8*)(qkv + qbase + 32);
        qb[3] = *(const short8*)(qkv + qbase + 48);
    }

    f32x16 acc0 = {}, acc1 = {};
    float m_run = -1e30f, l_run = 0.f;   // m_run in log2-scaled domain

    const int ntiles = (qt >> 1) + 1;

    auto STAGE = [&](int buf, int kt) {
        const int krow0 = kt * 64;
#pragma unroll
        for (int p = 0; p < 2; ++p) {
            const int c = p * 256 + tid;        // 0..511
            const int r = c >> 3, gk = c & 7;
            const int gs = gk ^ (r & 7);
            gload_lds16(qkv + krow_base + (size_t)(krow0 + r) * QKS + gs * 8,
                        &Ks[buf][c * 8]);
            gload_lds16(vt + vrow_base + (size_t)r * NROWS + krow0 + gs * 8,
                        &Vs[buf][c * 8]);
        }
    };

    STAGE(0, 0);
    asm volatile("s_waitcnt vmcnt(0)" ::: "memory");
    __syncthreads();

    for (int kt = 0; kt < ntiles; ++kt) {
        const int cur = kt & 1;
        if (kt + 1 < ntiles) STAGE(cur ^ 1, kt + 1);

        const int krow0 = kt * 64;
        const short* KsB = &Ks[cur][0];
        const short* VsB = &Vs[cur][0];

        // ---- S^T = K Q^T ----
        f32x16 s0 = {}, s1 = {};
        __builtin_amdgcn_s_setprio(1);
#pragma unroll
        for (int ks = 0; ks < 4; ++ks) {
            const int perm = ((2 * ks + hi) ^ (n & 7)) * 8;
            const short8 kf0 = *(const short8*)(KsB + n * 64 + perm);
            const short8 kf1 = *(const short8*)(KsB + (32 + n) * 64 + perm);
            s0 = mfma32(kf0, qb[ks], s0);
            s1 = mfma32(kf1, qb[ks], s1);
        }
        __builtin_amdgcn_s_setprio(0);

        // ---- causal mask (raw-score domain), only near the diagonal ----
        if (krow0 + 63 > Q0) {
#pragma unroll
            for (int r = 0; r < 16; ++r) {
                const int jj = krow0 + (r & 3) + 8 * (r >> 2) + 4 * hi;
                if (jj > qg) s0[r] = -1e30f;
                if (jj + 32 > qg) s1[r] = -1e30f;
            }
        }

        // ---- tree max (depth 5) + cross-half shfl ----
        float t8[8];
#pragma unroll
        for (int r = 0; r < 8; ++r)
            t8[r] = fmaxf(fmaxf(s0[r], s0[r + 8]), fmaxf(s1[r], s1[r + 8]));
        float mx = fmaxf(fmaxf(fmaxf(t8[0], t8[1]), fmaxf(t8[2], t8[3])),
                         fmaxf(fmaxf(t8[4], t8[5]), fmaxf(t8[6], t8[7])));
        mx = fmaxf(mx, __shfl_xor(mx, 32));
        const float pm = mx * KC;            // log2 domain

        // ---- defer-rescale (T13): skip when max growth <= 8 ----
        if (!__all(pm <= m_run + 8.0f)) {
            const float mn = fmaxf(m_run, pm);
            const float sc = __builtin_amdgcn_exp2f(m_run - mn);
            l_run *= sc;
#pragma unroll
            for (int r = 0; r < 16; ++r) { acc0[r] *= sc; acc1[r] *= sc; }
            m_run = mn;
        }

        // ---- P = exp2(s*KC - m_run), 4-way partial sums ----
        float ps[4] = {0.f, 0.f, 0.f, 0.f};
#pragma unroll
        for (int r = 0; r < 16; ++r) {
            const float p = __builtin_amdgcn_exp2f(__builtin_fmaf(s0[r], KC, -m_run));
            s0[r] = p; ps[r & 3] += p;
        }
#pragma unroll
        for (int r = 0; r < 16; ++r) {
            const float p = __builtin_amdgcn_exp2f(__builtin_fmaf(s1[r], KC, -m_run));
            s1[r] = p; ps[r & 3] += p;
        }
        float pst = (ps[0] + ps[1]) + (ps[2] + ps[3]);
        pst += __shfl_xor(pst, 32);
        l_run += pst;

        // ---- PV: O^T += V^T P^T (P-frags via cvt_pk + 2 permlane swaps) ----
        __builtin_amdgcn_s_setprio(1);
#define PV_STEP(KS, SV)                                                              \
        {                                                                            \
            const unsigned c01 = cvtpk_bf16(SV[((KS)&1)*8+0], SV[((KS)&1)*8+1]);     \
            const unsigned c23 = cvtpk_bf16(SV[((KS)&1)*8+2], SV[((KS)&1)*8+3]);     \
            const unsigned c45 = cvtpk_bf16(SV[((KS)&1)*8+4], SV[((KS)&1)*8+5]);     \
            const unsigned c67 = cvtpk_bf16(SV[((KS)&1)*8+6], SV[((KS)&1)*8+7]);     \
            const i32x2 r02 = __builtin_amdgcn_permlane32_swap((int)c01, (int)c45, false, false); \
            const i32x2 r13 = __builtin_amdgcn_permlane32_swap((int)c23, (int)c67, false, false); \
            const short8 pfrag = frag_from_u32((unsigned)r02.x, (unsigned)r13.x,     \
                                               (unsigned)r02.y, (unsigned)r13.y);    \
            const int permv = ((2 * (KS) + hi) ^ (n & 7)) * 8;                       \
            const short8 vf0 = *(const short8*)(VsB + n * 64 + permv);               \
            const short8 vf1 = *(const short8*)(VsB + (32 + n) * 64 + permv);        \
            acc0 = mfma32(vf0, pfrag, acc0);                                         \
            acc1 = mfma32(vf1, pfrag, acc1);                                         \
        }
        PV_STEP(0, s0)
        PV_STEP(1, s0)
        PV_STEP(2, s1)
        PV_STEP(3, s1)
#undef PV_STEP
        __builtin_amdgcn_s_setprio(0);

        asm volatile("s_waitcnt vmcnt(0)" ::: "memory");
        __syncthreads();
    }

    // ---- epilogue: O[q][d], d = dt*32 + rg*8 + hi*4 + (0..3) ----
    const float invl = 1.0f / l_run;
    const size_t orow = (size_t)(b * T_SEQ + qg) * 2048 + h * 64;
#pragma unroll
    for (int rg = 0; rg < 4; ++rg) {
        u32x2 pk0, pk1;
        pk0.x = cvtpk_bf16(acc0[rg * 4 + 0] * invl, acc0[rg * 4 + 1] * invl);
        pk0.y = cvtpk_bf16(acc0[rg * 4 + 2] * invl, acc0[rg * 4 + 3] * invl);
        pk1.x = cvtpk_bf16(acc1[rg * 4 + 0] * invl, acc1[rg * 4 + 1] * invl);
        pk1.y = cvtpk_bf16(acc1[rg * 4 + 2] * invl, acc1[rg * 4 + 3] * invl);
        *(u32x2*)(aout + orow + rg * 8 + hi * 4) = pk0;
        *(u32x2*)(aout + orow + 32 + rg * 8 + hi * 4) = pk1;
    }
}

// ---------------- launch ----------------
extern "C" void kernel_launch(void* const* d_in, const int* in_sizes, int n_in,
                              void* d_out, int out_size, void* d_ws, size_t ws_size,
                              hipStream_t stream) {
    const float* x    = (const float*)d_in[0];
    const float* fcos = (const float*)d_in[1];
    const float* fsin = (const float*)d_in[2];
    const float* wq   = (const float*)d_in[4];
    const float* wk   = (const float*)d_in[5];
    const float* wv   = (const float*)d_in[6];
    const float* wo   = (const float*)d_in[7];

    short* ws0  = (short*)d_ws;
    short* qkvb = ws0;                    // [0, 20MB): 4096 x 2560 (q|k)
    short* vt   = ws0 + 10485760;         // [20, 24MB): V^T 512 x 4096
    short* wT   = ws0 + 12582912;         // [24, 36MB): wq^T|wk^T|wv^T (3072 x 2048)
    short* vbuf = ws0 + 18874368;         // [36, 40MB): V 4096 x 512
    short* aout = ws0 + 12582912;         // [24, 40MB): attn out (after wT/vbuf dead)
    short* woT  = ws0;                    // [0, 8MB): wo^T (after qkvb dead)
    short* xb   = (short*)d_out;          // x as bf16 lives in d_out until GEMM2 rewrites it

    // 1. x -> bf16 (into d_out scratch)
    conv_f32_bf16<<<4096, 256, 0, stream>>>(x, xb);
    // 2. fused weight transposes (wq|wk|wv -> wT)
    trans_wqkv<<<dim3(96, 64), 256, 0, stream>>>(wq, wk, wv, wT);
    // 3. fused QKV projection: q,k -> qkvb (stride 2560); v -> vbuf (stride 512)
    gemm_mfma<0><<<dim3(24, 32), 256, 0, stream>>>(xb, wT, qkvb, QKS, vbuf, 2560,
                                                   NROWS, 3072, 2048);
    // 4. fused RoPE on q and k
    rope_fused<<<20480, 256, 0, stream>>>((unsigned short*)qkvb, fcos, fsin);
    // 5. V -> V^T
    transpose_bf16<<<dim3(16, 128), 256, 0, stream>>>(vbuf, vt, NROWS, 512);
    // 6. attention (GQA-native blocks: 4 heads/group share staging; 16 waves/CU)
    attn_fwd<<<1024, 256, 0, stream>>>(qkvb, vt, (unsigned short*)aout);
    // 7. wo^T (qkvb region dead now)
    transpose_f32_bf16<<<dim3(64, 64), 256, 0, stream>>>(wo, woT, 2048, 2048);
    // 8. output projection (xb in d_out is dead; GEMM2 overwrites all of d_out)
    gemm_mfma<1><<<dim3(16, 32), 256, 0, stream>>>(aout, woT, d_out, 2048, nullptr, 1 << 30,
                                                   NROWS, 2048, 2048);
}

// Round 8
// 218.559 us; speedup vs baseline: 17.9797x; 1.0581x over previous
//
#include <hip/hip_runtime.h>
#include <hip/hip_bf16.h>

#define T_SEQ 2048
#define NROWS 4096     // B*T
#define QKS   2560     // qkv buffer row stride: q(2048) + k(512)

typedef __attribute__((ext_vector_type(8))) short short8;
typedef __attribute__((ext_vector_type(4))) float f32x4;
typedef __attribute__((ext_vector_type(16))) float f32x16;
typedef __attribute__((ext_vector_type(2))) int i32x2;
typedef __attribute__((ext_vector_type(2))) unsigned int u32x2;

#define KC 0.18033688f   // 0.125 * log2(e)

__device__ __forceinline__ unsigned short f2bf(float f) {
    unsigned u = __builtin_bit_cast(unsigned, f);
    u += 0x7FFF + ((u >> 16) & 1);
    return (unsigned short)(u >> 16);
}
__device__ __forceinline__ float bf2f(unsigned short s) {
    unsigned u = ((unsigned)s) << 16;
    return __builtin_bit_cast(float, u);
}

__device__ __forceinline__ void gload_lds16(const void* g, void* l) {
    __builtin_amdgcn_global_load_lds(
        (const __attribute__((address_space(1))) unsigned int*)g,
        (__attribute__((address_space(3))) unsigned int*)l,
        16, 0, 0);
}

__device__ __forceinline__ f32x4 mfma16(short8 a, short8 b, f32x4 c) {
    return __builtin_amdgcn_mfma_f32_16x16x32_bf16(a, b, c, 0, 0, 0);
}
__device__ __forceinline__ f32x16 mfma32(short8 a, short8 b, f32x16 c) {
    return __builtin_amdgcn_mfma_f32_32x32x16_bf16(a, b, c, 0, 0, 0);
}

__device__ __forceinline__ unsigned cvtpk_bf16(float lo, float hi) {
    unsigned r;
    asm("v_cvt_pk_bf16_f32 %0, %1, %2" : "=v"(r) : "v"(lo), "v"(hi));
    return r;
}

__device__ __forceinline__ short8 frag_from_u32(unsigned w0, unsigned w1, unsigned w2, unsigned w3) {
    union { unsigned u[4]; short8 s; } t;
    t.u[0] = w0; t.u[1] = w1; t.u[2] = w2; t.u[3] = w3;
    return t.s;
}

// ---------------- fp32 -> bf16 convert (8 elems/thread, exact-size grid) ----------------
__global__ __launch_bounds__(256) void conv_f32_bf16(const float* __restrict__ S,
                                                     short* __restrict__ D) {
    const int i = blockIdx.x * 256 + threadIdx.x;
    const float4 a = ((const float4*)S)[i * 2];
    const float4 b = ((const float4*)S)[i * 2 + 1];
    ((short8*)D)[i] = frag_from_u32(cvtpk_bf16(a.x, a.y), cvtpk_bf16(a.z, a.w),
                                    cvtpk_bf16(b.x, b.y), cvtpk_bf16(b.z, b.w));
}

// ---------------- fused wq/wk/wv transpose: fp32[K][N] -> bf16 wT[N'][K] ----------------
// grid (96, 64): bx<64 -> wq (N=2048), 64..79 -> wk, 80..95 -> wv (N=512). K=2048.
__global__ __launch_bounds__(256) void trans_wqkv(const float* __restrict__ wq,
                                                  const float* __restrict__ wk,
                                                  const float* __restrict__ wv,
                                                  short* __restrict__ wT) {
    __shared__ float tile[32][33];
    const int bx = blockIdx.x, by = blockIdx.y;
    const float* S; int srcN, nt, dstRow0;
    if (bx < 64)      { S = wq; srcN = 2048; nt = bx;      dstRow0 = 0;    }
    else if (bx < 80) { S = wk; srcN = 512;  nt = bx - 64; dstRow0 = 2048; }
    else              { S = wv; srcN = 512;  nt = bx - 80; dstRow0 = 2560; }
    const int n0 = nt * 32, k0 = by * 32;
    const int t = threadIdx.x;
#pragma unroll
    for (int j = 0; j < 4; ++j) {
        int lin = t + 256 * j;
        int kk = lin >> 5, nn = lin & 31;
        tile[kk][nn] = S[(size_t)(k0 + kk) * srcN + n0 + nn];
    }
    __syncthreads();
#pragma unroll
    for (int j = 0; j < 4; ++j) {
        int lin = t + 256 * j;
        int nn = lin >> 5, kk = lin & 31;
        wT[(size_t)(dstRow0 + n0 + nn) * 2048 + k0 + kk] = (short)f2bf(tile[kk][nn]);
    }
}

// ---------------- single-source transpose fp32[K][N] -> bf16[N][K] (wo) ----------------
__global__ __launch_bounds__(256) void transpose_f32_bf16(const float* __restrict__ S,
                                                          short* __restrict__ D,
                                                          int K, int N) {
    __shared__ float tile[32][33];
    const int n0 = blockIdx.x * 32, k0 = blockIdx.y * 32;
    const int t = threadIdx.x;
#pragma unroll
    for (int j = 0; j < 4; ++j) {
        int lin = t + 256 * j;
        int kk = lin >> 5, nn = lin & 31;
        tile[kk][nn] = S[(size_t)(k0 + kk) * N + n0 + nn];
    }
    __syncthreads();
#pragma unroll
    for (int j = 0; j < 4; ++j) {
        int lin = t + 256 * j;
        int nn = lin >> 5, kk = lin & 31;
        D[(size_t)(n0 + nn) * K + k0 + kk] = (short)f2bf(tile[kk][nn]);
    }
}

// ---------------- transpose bf16[R][C] -> bf16[C][R] ----------------
__global__ __launch_bounds__(256) void transpose_bf16(const short* __restrict__ S,
                                                      short* __restrict__ D,
                                                      int R, int Cc) {
    __shared__ short tile[32][33];
    const int c0 = blockIdx.x * 32, r0 = blockIdx.y * 32;
    const int t = threadIdx.x;
#pragma unroll
    for (int j = 0; j < 4; ++j) {
        int lin = t + 256 * j;
        int rr = lin >> 5, cc = lin & 31;
        tile[rr][cc] = S[(size_t)(r0 + rr) * Cc + c0 + cc];
    }
    __syncthreads();
#pragma unroll
    for (int j = 0; j < 4; ++j) {
        int lin = t + 256 * j;
        int cc = lin >> 5, rr = lin & 31;
        D[(size_t)(c0 + cc) * R + r0 + rr] = tile[rr][cc];
    }
}

// ---------------- fused RoPE over q and k regions of qkvb ----------------
// idx < 4194304 -> q (Hn=32, c0=0); else k (Hn=8, c0=2048). Stride QKS.
__global__ __launch_bounds__(256) void rope_fused(unsigned short* __restrict__ t,
                                                  const float* __restrict__ cosp,
                                                  const float* __restrict__ sinp) {
    int idx = blockIdx.x * 256 + threadIdx.x;
    int Hn = 32, c0 = 0;
    if (idx >= 4194304) { idx -= 4194304; Hn = 8; c0 = 2048; }
    const int p = idx & 31;
    const int hh = (idx >> 5) % Hn;
    const int row = idx / (32 * Hn);
    const int tpos = row & (T_SEQ - 1);
    const float c = cosp[tpos * 32 + p];
    const float s = sinp[tpos * 32 + p];
    const size_t base = (size_t)row * QKS + c0 + hh * 64 + 2 * p;
    float e = bf2f(t[base]), o = bf2f(t[base + 1]);
    t[base]     = f2bf(e * c - o * s);
    t[base + 1] = f2bf(e * s + o * c);
}

// ---------------- MFMA GEMM: C[M,N] = A[M,K] @ Bt[N,K]^T ----------------
// 128x128 tile, BK=32, 4 waves (2x2), linear LDS, dual gload_lds.
// 2-phase double-buffered pipeline (T3-min): STAGE(next) issued BEFORE compute(cur),
// one vmcnt(0)+barrier per K-step -> staging latency hides under MFMA.
// XCD-aware bijective block swizzle (requires nwg % 8 == 0).
// cols >= nsplit go (bf16) to Cv with row stride 512 at col-nsplit.
template <int STORE_F32>
__global__ __launch_bounds__(256) void gemm_mfma(const short* __restrict__ A,
                                                 const short* __restrict__ Bt,
                                                 void* __restrict__ C, int ldc,
                                                 short* __restrict__ Cv, int nsplit,
                                                 int M, int N, int K) {
    __shared__ short As[2][128 * 32];
    __shared__ short Bs[2][128 * 32];
    const int tid = threadIdx.x;
    const int l = tid & 63, w = tid >> 6;
    const int wr = w >> 1, wc = w & 1;
    const int lm = l & 15, lg = l >> 4;

    // XCD swizzle: contiguous tile chunk per XCD
    const int nwg = gridDim.x * gridDim.y;
    int bid = blockIdx.y * gridDim.x + blockIdx.x;
    bid = (bid & 7) * (nwg >> 3) + (bid >> 3);
    const int row0 = (bid / gridDim.x) * 128;
    const int col0 = (bid % gridDim.x) * 128;

    f32x4 acc[4][4];
#pragma unroll
    for (int m = 0; m < 4; ++m)
#pragma unroll
        for (int n = 0; n < 4; ++n) acc[m][n] = (f32x4){0.f, 0.f, 0.f, 0.f};

    auto STAGE = [&](int buf, int kt) {
        const int k0 = kt * 32;
#pragma unroll
        for (int p = 0; p < 2; ++p) {
            const int c = tid + 256 * p;          // 0..511
            const int r = c >> 2, k8 = (c & 3) * 8;
            gload_lds16(A  + (size_t)(row0 + r) * K + k0 + k8, &As[buf][c * 8]);
            gload_lds16(Bt + (size_t)(col0 + r) * K + k0 + k8, &Bs[buf][c * 8]);
        }
    };

    const int nk = K >> 5;
    STAGE(0, 0);
    asm volatile("s_waitcnt vmcnt(0)" ::: "memory");
    __syncthreads();

    for (int kt = 0; kt < nk; ++kt) {
        const int cur = kt & 1;
        if (kt + 1 < nk) STAGE(cur ^ 1, kt + 1);

        short8 af[4], bfr[4];
#pragma unroll
        for (int m = 0; m < 4; ++m)
            af[m] = *(const short8*)(&As[cur][(wr * 64 + m * 16 + lm) * 32 + lg * 8]);
#pragma unroll
        for (int n = 0; n < 4; ++n)
            bfr[n] = *(const short8*)(&Bs[cur][(wc * 64 + n * 16 + lm) * 32 + lg * 8]);
#pragma unroll
        for (int m = 0; m < 4; ++m)
#pragma unroll
            for (int n = 0; n < 4; ++n)
                acc[m][n] = mfma16(af[m], bfr[n], acc[m][n]);

        asm volatile("s_waitcnt vmcnt(0)" ::: "memory");
        __syncthreads();
    }

    const bool vreg = (!STORE_F32) && (col0 >= nsplit);
#pragma unroll
    for (int m = 0; m < 4; ++m)
#pragma unroll
        for (int n = 0; n < 4; ++n) {
            if (vreg) {
#pragma unroll
                for (int r = 0; r < 4; ++r) {
                    const int row = row0 + wr * 64 + m * 16 + lg * 4 + r;
                    const int col = col0 + wc * 64 + n * 16 + lm - nsplit;
                    Cv[(size_t)row * 512 + col] = (short)f2bf(acc[m][n][r]);
                }
            } else {
#pragma unroll
                for (int r = 0; r < 4; ++r) {
                    const int row = row0 + wr * 64 + m * 16 + lg * 4 + r;
                    const int col = col0 + wc * 64 + n * 16 + lm;
                    const float v = acc[m][n][r];
                    if (STORE_F32) ((float*)C)[(size_t)row * ldc + col] = v;
                    else ((unsigned short*)C)[(size_t)row * ldc + col] = f2bf(v);
                }
            }
        }
}

// ---------------- MFMA flash attention (causal, GQA 4:1), 32x32x16 ----------------
// grid (1024): block = one 32-row q-subtile x all 4 heads of one KV group.
// 4 waves = 4 heads (share K/V staging exactly); wave q rows [qt*32, +32).
// bid -> (qt, g, b) via quadrant-XOR mapping: per-CU qt-sum is constant (126)
// for BOTH contiguous x4 and stride-256 XCD round-robin block->CU assignment.
// S^T = K.Q^T; lane-local softmax (exp2, tree, defer-rescale); P-frags via
// cvt_pk + 2x permlane32_swap; O^T = V^T.P^T. n = l&31 (q), hi = l>>5.
__global__ __launch_bounds__(256, 4) void attn_fwd(const short* __restrict__ qkv,
                                                   const short* __restrict__ vt,
                                                   unsigned short* __restrict__ aout) {
    __shared__ short Ks[2][64 * 64];
    __shared__ short Vs[2][64 * 64];
    const int bid = blockIdx.x;
    const int q2 = (bid & 3) ^ ((bid >> 8) & 3);
    const int t  = (bid >> 2) & 15;
    const int gb = ((bid >> 6) & 3) | (((bid >> 8) & 3) << 2);
    const int qt = (q2 == 0) ? t : (q2 == 1) ? (31 - t) : (q2 == 2) ? (32 + t) : (63 - t);
    const int g = gb & 7, b = gb >> 3;

    const int tid = threadIdx.x, l = tid & 63, w = tid >> 6;
    const int n = l & 31, hi = l >> 5;
    const int h = g * 4 + w;            // each wave: its own head of this KV group
    const int Q0 = qt * 32;
    const int qg = Q0 + n;

    const size_t krow_base = (size_t)(b * T_SEQ) * QKS + 2048 + g * 64;
    const size_t vrow_base = (size_t)(g * 64) * NROWS + b * T_SEQ;

    short8 qb[4];
    {
        const size_t qbase = (size_t)(b * T_SEQ + qg) * QKS + h * 64 + hi * 8;
        qb[0] = *(const short8*)(qkv + qbase);
        qb[1] = *(const short8*)(qkv + qbase + 16);
        qb[2] = *(const short8*)(qkv + qbase + 32);
        qb[3] = *(const short8*)(qkv + qbase + 48);
    }

    f32x16 acc0 = {}, acc1 = {};
    float m_run = -1e30f, l_run = 0.f;   // m_run in log2-scaled domain

    const int ntiles = (qt >> 1) + 1;

    auto STAGE = [&](int buf, int kt) {
        const int krow0 = kt * 64;
#pragma unroll
        for (int p = 0; p < 2; ++p) {
            const int c = p * 256 + tid;        // 0..511
            const int r = c >> 3, gk = c & 7;
            const int gs = gk ^ (r & 7);
            gload_lds16(qkv + krow_base + (size_t)(krow0 + r) * QKS + gs * 8,
                        &Ks[buf][c * 8]);
            gload_lds16(vt + vrow_base + (size_t)r * NROWS + krow0 + gs * 8,
                        &Vs[buf][c * 8]);
        }
    };

    STAGE(0, 0);
    asm volatile("s_waitcnt vmcnt(0)" ::: "memory");
    __syncthreads();

    for (int kt = 0; kt < ntiles; ++kt) {
        const int cur = kt & 1;
        if (kt + 1 < ntiles) STAGE(cur ^ 1, kt + 1);

        const int krow0 = kt * 64;
        const short* KsB = &Ks[cur][0];
        const short* VsB = &Vs[cur][0];

        // ---- S^T = K Q^T ----
        f32x16 s0 = {}, s1 = {};
        __builtin_amdgcn_s_setprio(1);
#pragma unroll
        for (int ks = 0; ks < 4; ++ks) {
            const int perm = ((2 * ks + hi) ^ (n & 7)) * 8;
            const short8 kf0 = *(const short8*)(KsB + n * 64 + perm);
            const short8 kf1 = *(const short8*)(KsB + (32 + n) * 64 + perm);
            s0 = mfma32(kf0, qb[ks], s0);
            s1 = mfma32(kf1, qb[ks], s1);
        }
        __builtin_amdgcn_s_setprio(0);

        // ---- causal mask (raw-score domain), only near the diagonal ----
        if (krow0 + 63 > Q0) {
#pragma unroll
            for (int r = 0; r < 16; ++r) {
                const int jj = krow0 + (r & 3) + 8 * (r >> 2) + 4 * hi;
                if (jj > qg) s0[r] = -1e30f;
                if (jj + 32 > qg) s1[r] = -1e30f;
            }
        }

        // ---- tree max (depth 5) + cross-half shfl ----
        float t8[8];
#pragma unroll
        for (int r = 0; r < 8; ++r)
            t8[r] = fmaxf(fmaxf(s0[r], s0[r + 8]), fmaxf(s1[r], s1[r + 8]));
        float mx = fmaxf(fmaxf(fmaxf(t8[0], t8[1]), fmaxf(t8[2], t8[3])),
                         fmaxf(fmaxf(t8[4], t8[5]), fmaxf(t8[6], t8[7])));
        mx = fmaxf(mx, __shfl_xor(mx, 32));
        const float pm = mx * KC;            // log2 domain

        // ---- defer-rescale (T13): skip when max growth <= 8 ----
        if (!__all(pm <= m_run + 8.0f)) {
            const float mn = fmaxf(m_run, pm);
            const float sc = __builtin_amdgcn_exp2f(m_run - mn);
            l_run *= sc;
#pragma unroll
            for (int r = 0; r < 16; ++r) { acc0[r] *= sc; acc1[r] *= sc; }
            m_run = mn;
        }

        // ---- P = exp2(s*KC - m_run), 4-way partial sums ----
        float ps[4] = {0.f, 0.f, 0.f, 0.f};
#pragma unroll
        for (int r = 0; r < 16; ++r) {
            const float p = __builtin_amdgcn_exp2f(__builtin_fmaf(s0[r], KC, -m_run));
            s0[r] = p; ps[r & 3] += p;
        }
#pragma unroll
        for (int r = 0; r < 16; ++r) {
            const float p = __builtin_amdgcn_exp2f(__builtin_fmaf(s1[r], KC, -m_run));
            s1[r] = p; ps[r & 3] += p;
        }
        float pst = (ps[0] + ps[1]) + (ps[2] + ps[3]);
        pst += __shfl_xor(pst, 32);
        l_run += pst;

        // ---- PV: O^T += V^T P^T (P-frags via cvt_pk + 2 permlane swaps) ----
        __builtin_amdgcn_s_setprio(1);
#define PV_STEP(KS, SV)                                                              \
        {                                                                            \
            const unsigned c01 = cvtpk_bf16(SV[((KS)&1)*8+0], SV[((KS)&1)*8+1]);     \
            const unsigned c23 = cvtpk_bf16(SV[((KS)&1)*8+2], SV[((KS)&1)*8+3]);     \
            const unsigned c45 = cvtpk_bf16(SV[((KS)&1)*8+4], SV[((KS)&1)*8+5]);     \
            const unsigned c67 = cvtpk_bf16(SV[((KS)&1)*8+6], SV[((KS)&1)*8+7]);     \
            const i32x2 r02 = __builtin_amdgcn_permlane32_swap((int)c01, (int)c45, false, false); \
            const i32x2 r13 = __builtin_amdgcn_permlane32_swap((int)c23, (int)c67, false, false); \
            const short8 pfrag = frag_from_u32((unsigned)r02.x, (unsigned)r13.x,     \
                                               (unsigned)r02.y, (unsigned)r13.y);    \
            const int permv = ((2 * (KS) + hi) ^ (n & 7)) * 8;                       \
            const short8 vf0 = *(const short8*)(VsB + n * 64 + permv);               \
            const short8 vf1 = *(const short8*)(VsB + (32 + n) * 64 + permv);        \
            acc0 = mfma32(vf0, pfrag, acc0);                                         \
            acc1 = mfma32(vf1, pfrag, acc1);                                         \
        }
        PV_STEP(0, s0)
        PV_STEP(1, s0)
        PV_STEP(2, s1)
        PV_STEP(3, s1)
#undef PV_STEP
        __builtin_amdgcn_s_setprio(0);

        asm volatile("s_waitcnt vmcnt(0)" ::: "memory");
        __syncthreads();
    }

    // ---- epilogue: O[q][d], d = dt*32 + rg*8 + hi*4 + (0..3) ----
    const float invl = 1.0f / l_run;
    const size_t orow = (size_t)(b * T_SEQ + qg) * 2048 + h * 64;
#pragma unroll
    for (int rg = 0; rg < 4; ++rg) {
        u32x2 pk0, pk1;
        pk0.x = cvtpk_bf16(acc0[rg * 4 + 0] * invl, acc0[rg * 4 + 1] * invl);
        pk0.y = cvtpk_bf16(acc0[rg * 4 + 2] * invl, acc0[rg * 4 + 3] * invl);
        pk1.x = cvtpk_bf16(acc1[rg * 4 + 0] * invl, acc1[rg * 4 + 1] * invl);
        pk1.y = cvtpk_bf16(acc1[rg * 4 + 2] * invl, acc1[rg * 4 + 3] * invl);
        *(u32x2*)(aout + orow + rg * 8 + hi * 4) = pk0;
        *(u32x2*)(aout + orow + 32 + rg * 8 + hi * 4) = pk1;
    }
}

// ---------------- launch ----------------
extern "C" void kernel_launch(void* const* d_in, const int* in_sizes, int n_in,
                              void* d_out, int out_size, void* d_ws, size_t ws_size,
                              hipStream_t stream) {
    const float* x    = (const float*)d_in[0];
    const float* fcos = (const float*)d_in[1];
    const float* fsin = (const float*)d_in[2];
    const float* wq   = (const float*)d_in[4];
    const float* wk   = (const float*)d_in[5];
    const float* wv   = (const float*)d_in[6];
    const float* wo   = (const float*)d_in[7];

    short* ws0  = (short*)d_ws;
    short* qkvb = ws0;                    // [0, 20MB): 4096 x 2560 (q|k)
    short* vt   = ws0 + 10485760;         // [20, 24MB): V^T 512 x 4096
    short* wT   = ws0 + 12582912;         // [24, 36MB): wq^T|wk^T|wv^T (3072 x 2048)
    short* vbuf = ws0 + 18874368;         // [36, 40MB): V 4096 x 512
    short* aout = ws0 + 12582912;         // [24, 40MB): attn out (after wT/vbuf dead)
    short* woT  = ws0;                    // [0, 8MB): wo^T (after qkvb dead)
    short* xb   = (short*)d_out;          // x as bf16 lives in d_out until GEMM2 rewrites it

    // 1. x -> bf16 (into d_out scratch)
    conv_f32_bf16<<<4096, 256, 0, stream>>>(x, xb);
    // 2. fused weight transposes (wq|wk|wv -> wT)
    trans_wqkv<<<dim3(96, 64), 256, 0, stream>>>(wq, wk, wv, wT);
    // 3. fused QKV projection: q,k -> qkvb (stride 2560); v -> vbuf (stride 512)
    gemm_mfma<0><<<dim3(24, 32), 256, 0, stream>>>(xb, wT, qkvb, QKS, vbuf, 2560,
                                                   NROWS, 3072, 2048);
    // 4. fused RoPE on q and k
    rope_fused<<<20480, 256, 0, stream>>>((unsigned short*)qkvb, fcos, fsin);
    // 5. V -> V^T
    transpose_bf16<<<dim3(16, 128), 256, 0, stream>>>(vbuf, vt, NROWS, 512);
    // 6. attention (GQA-native blocks: 4 heads/group share staging; 16 waves/CU)
    attn_fwd<<<1024, 256, 0, stream>>>(qkvb, vt, (unsigned short*)aout);
    // 7. wo^T (qkvb region dead now)
    transpose_f32_bf16<<<dim3(64, 64), 256, 0, stream>>>(wo, woT, 2048, 2048);
    // 8. output projection (xb in d_out is dead; GEMM2 overwrites all of d_out)
    gemm_mfma<1><<<dim3(16, 32), 256, 0, stream>>>(aout, woT, d_out, 2048, nullptr, 1 << 30,
                                                   NROWS, 2048, 2048);
}